// Round 9
// baseline (323.972 us; speedup 1.0000x reference)
//
#include <hip/hip_runtime.h>

#define EPS 1e-3f

typedef __attribute__((ext_vector_type(8))) short bf8_t;   // 8 bf16 (4 VGPRs)
typedef __attribute__((ext_vector_type(4))) float f32x4;   // MFMA acc

static __device__ __forceinline__ unsigned f2bf_pack(float a, float b) {
  union { float f; unsigned u; } ca, cb;
  ca.f = a; cb.f = b;
  unsigned ra = (ca.u + 0x7FFFu + ((ca.u >> 16) & 1u)) >> 16;
  unsigned rb = (cb.u + 0x7FFFu + ((cb.u >> 16) & 1u)) >> 16;
  return ra | (rb << 16);
}
static __device__ __forceinline__ unsigned short f2bf1(float x) {
  union { float f; unsigned u; } c; c.f = x;
  return (unsigned short)((c.u + 0x7FFFu + ((c.u >> 16) & 1u)) >> 16);
}
static __device__ __forceinline__ float bf2f(unsigned bits16) {
  union { unsigned u; float f; } c;
  c.u = bits16 << 16;
  return c.f;
}

// ===========================================================================
// FULL (MFMA + bf16) PATH — destination-compacted messages (msgs only),
// center fused with combine+stats (128-row tile, stride-132 rowbuf,
// 16-lane-group combine, msg-0 register prefetch).
// ws layout: [0,32KB) padded stats (sum[c] @ c*16 floats, sumsq @ 4096+c*16,
//            gtot @ byte 28672) | cnt (@32KB, one memset covers both) | BC |
//            SL | fbuf | Wb | compact | outb
// Dispatches: memset | prep | prefix | msg | center_combine | norm  (6)
// ===========================================================================

// fused: Wb transpose-convert | feats fp32->bf16 fbuf | per-(tap,p) slot grab
__global__ __launch_bounds__(256) void prep(
    const float* __restrict__ W, unsigned short* __restrict__ Wb,
    const float* __restrict__ f1, const float* __restrict__ f2,
    unsigned short* __restrict__ fbuf,
    const int* __restrict__ S, unsigned char* __restrict__ SL,
    int* __restrict__ cnt, int N, int N1, int pm,
    int wblocks, int fblocks, int cpb) {
  const int bid = blockIdx.x;
  if (bid < wblocks) {
    // W[27][64][128] fp32 -> Wb[27][128][64] bf16 (27*128*64 = 864 blocks)
    int idx = bid * 256 + threadIdx.x;
    int k = idx & 63, n = (idx >> 6) & 127, t = idx >> 13;
    Wb[idx] = f2bf1(W[((size_t)t * 64 + k) * 128 + n]);
  } else if (bid < wblocks + fblocks) {
    // feats (f1|f2) fp32 -> fbuf bf16, (N+1) rows x 64, row N = zeros
    int idx = (bid - wblocks) * 256 + threadIdx.x;  // (N+1)*8 segs of 8
    if (idx >= (N + 1) * 8) return;
    int row = idx >> 3, seg = idx & 7;
    uint4 o = make_uint4(0, 0, 0, 0);
    if (row < N) {
      const float* src = (row < N1) ? (f1 + (size_t)row * 64)
                                    : (f2 + (size_t)(row - N1) * 64);
      float4 v0 = *(const float4*)(src + seg * 8);
      float4 v1 = *(const float4*)(src + seg * 8 + 4);
      o.x = f2bf_pack(v0.x, v0.y); o.y = f2bf_pack(v0.z, v0.w);
      o.z = f2bf_pack(v1.x, v1.y); o.w = f2bf_pack(v1.z, v1.w);
    }
    *(uint4*)(fbuf + (size_t)idx * 8) = o;
  } else {
    int b = bid - wblocks - fblocks;
    int tap = b / cpb;
    int p = (b - tap * cpb) * 256 + threadIdx.x;
    if (p >= pm) return;
    const int idx = tap * pm + p;
    const int s = S[idx];
    if (s < N) SL[idx] = (unsigned char)atomicAdd(&cnt[s], 1);  // max 26/row
  }
}

// exclusive prefix over cnt -> BC[j] = (base, cnt). Block order arbitrary
// (atomic chunk base) but stored, hence consistent for all consumers.
__global__ __launch_bounds__(256) void prefix_base(
    const int* __restrict__ cnt, int2* __restrict__ BC,
    int* __restrict__ gtot, int N) {
  const int t = threadIdx.x;
  const int j0 = blockIdx.x * 1024 + t * 4;
  int c0 = 0, c1 = 0, c2 = 0, c3 = 0;
  if (j0 + 3 < N) {
    int4 c = *(const int4*)(cnt + j0);
    c0 = c.x; c1 = c.y; c2 = c.z; c3 = c.w;
  } else {
    if (j0 < N) c0 = cnt[j0];
    if (j0 + 1 < N) c1 = cnt[j0 + 1];
    if (j0 + 2 < N) c2 = cnt[j0 + 2];
  }
  const int tsum = c0 + c1 + c2 + c3;
  int incl = tsum;
#pragma unroll
  for (int off = 1; off < 64; off <<= 1) {
    int u = __shfl_up(incl, off, 64);
    if ((t & 63) >= off) incl += u;
  }
  __shared__ int wsum[4];
  if ((t & 63) == 63) wsum[t >> 6] = incl;
  __syncthreads();
  if (t == 0) {
    int w0 = wsum[0], w1 = wsum[1], w2 = wsum[2], w3 = wsum[3];
    int gb = atomicAdd(gtot, w0 + w1 + w2 + w3);
    wsum[0] = gb; wsum[1] = gb + w0;
    wsum[2] = gb + w0 + w1; wsum[3] = gb + w0 + w1 + w2;
  }
  __syncthreads();
  const int excl = wsum[t >> 6] + incl - tsum;
  if (j0 < N) BC[j0] = make_int2(excl, c0);
  if (j0 + 1 < N) BC[j0 + 1] = make_int2(excl + c0, c1);
  if (j0 + 2 < N) BC[j0 + 2] = make_int2(excl + c0 + c1, c2);
  if (j0 + 3 < N) BC[j0 + 3] = make_int2(excl + c0 + c1 + c2, c3);
}

// 26 neighbor taps -> compact[(BC[s].x + SL[tap,p])*128 + col]
__global__ __launch_bounds__(256) void msg_mfma_c(
    const unsigned short* __restrict__ fbuf,
    const unsigned short* __restrict__ Wb,
    const int* __restrict__ G, const int* __restrict__ S,
    const int2* __restrict__ BC, const unsigned char* __restrict__ SL,
    unsigned short* __restrict__ compact, int N, int pm) {
  const int tap = blockIdx.y;                 // tap index (0..25)
  const int ktap = tap + (tap >= 13 ? 1 : 0);
  const unsigned short* Wt = Wb + (size_t)ktap * 128 * 64;
  const int* Gi = G + (size_t)tap * pm;
  const int* Si = S + (size_t)tap * pm;
  const int p0 = blockIdx.x * 128;
  if (Gi[p0] >= N) return;  // fully-padded tail block (padding G == N)

  __shared__ unsigned short A[128 * 64];
  __shared__ int g_lds[128];
  __shared__ int d_lds[128];
  const int tid = threadIdx.x;
  if (tid < 128) {
    int p = p0 + tid;
    int g = N, d = -1;
    if (p < pm) {
      g = Gi[p];
      int s = Si[p];
      if (s < N) d = BC[s].x + (int)SL[(size_t)tap * pm + p];
    }
    g_lds[tid] = g;
    d_lds[tid] = d;
  }
  __syncthreads();

#pragma unroll
  for (int it = 0; it < 4; ++it) {
    int flat = it * 256 + tid;       // 128 rows x 8 segs of 8 bf16
    int r = flat >> 3, qs = flat & 7;
    int g = g_lds[r];                 // g in [0,N]; row N is zeros
    uint4 v = *(const uint4*)(fbuf + (size_t)g * 64 + qs * 8);
    int rt = r >> 4, m = r & 15, c = qs >> 2, qq = qs & 3;
    *(uint4*)(A + ((rt * 2 + c) * 64 + qq * 16 + m) * 8) = v;
  }
  __syncthreads();

  const int wave = tid >> 6, lane = tid & 63;
  const int ncol = lane & 15, q2 = lane >> 4;
  bf8_t Bf[2][2];
#pragma unroll
  for (int ct = 0; ct < 2; ++ct) {
    int col = wave * 32 + ct * 16 + ncol;
#pragma unroll
    for (int c = 0; c < 2; ++c)
      Bf[ct][c] = *(const bf8_t*)(Wt + (size_t)col * 64 + c * 32 + q2 * 8);
  }
  f32x4 acc[8][2];
#pragma unroll
  for (int rt = 0; rt < 8; ++rt)
#pragma unroll
    for (int ct = 0; ct < 2; ++ct) acc[rt][ct] = (f32x4){0.f, 0.f, 0.f, 0.f};

#pragma unroll
  for (int rt = 0; rt < 8; ++rt) {
    bf8_t a0 = *(const bf8_t*)(A + ((rt * 2 + 0) * 64 + lane) * 8);
    bf8_t a1 = *(const bf8_t*)(A + ((rt * 2 + 1) * 64 + lane) * 8);
#pragma unroll
    for (int ct = 0; ct < 2; ++ct) {
      acc[rt][ct] = __builtin_amdgcn_mfma_f32_16x16x32_bf16(a0, Bf[ct][0], acc[rt][ct], 0, 0, 0);
      acc[rt][ct] = __builtin_amdgcn_mfma_f32_16x16x32_bf16(a1, Bf[ct][1], acc[rt][ct], 0, 0, 0);
    }
  }

#pragma unroll
  for (int rt = 0; rt < 8; ++rt) {
    int dl[4];
#pragma unroll
    for (int e = 0; e < 4; ++e) dl[e] = d_lds[rt * 16 + q2 * 4 + e];
#pragma unroll
    for (int ct = 0; ct < 2; ++ct) {
      int col = wave * 32 + ct * 16 + ncol;
#pragma unroll
      for (int e = 0; e < 4; ++e)
        if (dl[e] >= 0)
          compact[(size_t)dl[e] * 128 + col] = f2bf1(acc[rt][ct][e]);
    }
  }
}

// center MFMA + coalesced message combine + stats, one kernel (128-row tile).
// Phase 1: stage 128 center rows (bf16) into SH[:16K], MFMA (8 rt).
//          BC for this thread's 8 combine-rows loaded to regs at start.
// Phase 2: msg-0 prefetch (uint4/row) issued right after MFMA -> latency
//          hides under park + barrier. Park center+bias in SH[128][132].
// Phase 3: 16 x 16-lane groups, 8 rows each: center from LDS + prefetched
//          msg0 + remaining compact rows (uint4/lane) -> outb + stats.
__global__ __launch_bounds__(256) void center_combine(
    const unsigned short* __restrict__ fbuf,
    const unsigned short* __restrict__ Wb13, const float* __restrict__ bias,
    const int2* __restrict__ BC, const unsigned short* __restrict__ compact,
    unsigned short* __restrict__ outb, float* __restrict__ ws, int N) {
  __shared__ unsigned short SH[128 * 132];  // 33 KB; [:16K) doubles as A
  const int tid = threadIdx.x;
  const int row0 = blockIdx.x * 128;

  // combine-phase geometry fixed up front; BC held in registers
  const int grp = tid >> 4, l = tid & 15;
  int2 bcr[8];
#pragma unroll
  for (int i = 0; i < 8; ++i) {
    int j = row0 + grp * 8 + i;
    bcr[i] = (j < N) ? BC[j] : make_int2(0, 0);
  }

  // ---- stage A (center rows, sequential fbuf reads): 128 rows x 8 segs ----
#pragma unroll
  for (int it = 0; it < 4; ++it) {
    int flat = it * 256 + tid;
    int r = flat >> 3, qs = flat & 7;
    int g = row0 + r; if (g >= N) g = N;  // row N is zeros
    uint4 v = *(const uint4*)(fbuf + (size_t)g * 64 + qs * 8);
    int rt = r >> 4, m = r & 15, c = qs >> 2, qq = qs & 3;
    *(uint4*)(SH + ((rt * 2 + c) * 64 + qq * 16 + m) * 8) = v;
  }
  __syncthreads();

  const int wave = tid >> 6, lane = tid & 63;
  const int ncol = lane & 15, q2 = lane >> 4;
  bf8_t Bf[2][2];
  float bs[2];
#pragma unroll
  for (int ct = 0; ct < 2; ++ct) {
    int col = wave * 32 + ct * 16 + ncol;
    bs[ct] = bias[col];
#pragma unroll
    for (int c = 0; c < 2; ++c)
      Bf[ct][c] = *(const bf8_t*)(Wb13 + (size_t)col * 64 + c * 32 + q2 * 8);
  }
  f32x4 acc[8][2];
#pragma unroll
  for (int rt = 0; rt < 8; ++rt)
#pragma unroll
    for (int ct = 0; ct < 2; ++ct) acc[rt][ct] = (f32x4){0.f, 0.f, 0.f, 0.f};

#pragma unroll
  for (int rt = 0; rt < 8; ++rt) {
    bf8_t a0 = *(const bf8_t*)(SH + ((rt * 2 + 0) * 64 + lane) * 8);
    bf8_t a1 = *(const bf8_t*)(SH + ((rt * 2 + 1) * 64 + lane) * 8);
#pragma unroll
    for (int ct = 0; ct < 2; ++ct) {
      acc[rt][ct] = __builtin_amdgcn_mfma_f32_16x16x32_bf16(a0, Bf[ct][0], acc[rt][ct], 0, 0, 0);
      acc[rt][ct] = __builtin_amdgcn_mfma_f32_16x16x32_bf16(a1, Bf[ct][1], acc[rt][ct], 0, 0, 0);
    }
  }

  // ---- msg-0 prefetch: issue now; latency hides under park + barrier ----
  uint4 pf[8];
#pragma unroll
  for (int i = 0; i < 8; ++i) {
    uint4 m = make_uint4(0, 0, 0, 0);
    if (bcr[i].y > 0)
      m = ((const uint4*)(compact + (size_t)bcr[i].x * 128))[l];
    pf[i] = m;
  }

  __syncthreads();  // all A reads done; SH becomes rowbuf (stride 132)

  // ---- park bf16(center+bias) into rowbuf SH[row][col], stride 132 ----
#pragma unroll
  for (int rt = 0; rt < 8; ++rt)
#pragma unroll
    for (int ct = 0; ct < 2; ++ct) {
      int col = wave * 32 + ct * 16 + ncol;
#pragma unroll
      for (int e = 0; e < 4; ++e)
        SH[(rt * 16 + q2 * 4 + e) * 132 + col] = f2bf1(acc[rt][ct][e] + bs[ct]);
    }
  __syncthreads();

  // ---- coalesced combine: 16 groups x 8 rows, uint4 (16 B) per lane ----
  float s[8], q[8];
#pragma unroll
  for (int c = 0; c < 8; ++c) { s[c] = 0.f; q[c] = 0.f; }
#pragma unroll 2
  for (int i = 0; i < 8; ++i) {
    int r = grp * 8 + i;
    int j = row0 + r;
    if (j < N) {
      int2 bc = bcr[i];
      uint4 cv = *(const uint4*)(SH + r * 132 + l * 8);
      float v[8];
      v[0] = bf2f(cv.x & 0xffffu); v[1] = bf2f(cv.x >> 16);
      v[2] = bf2f(cv.y & 0xffffu); v[3] = bf2f(cv.y >> 16);
      v[4] = bf2f(cv.z & 0xffffu); v[5] = bf2f(cv.z >> 16);
      v[6] = bf2f(cv.w & 0xffffu); v[7] = bf2f(cv.w >> 16);
      if (bc.y > 0) {
        uint4 mv = pf[i];
        v[0] += bf2f(mv.x & 0xffffu); v[1] += bf2f(mv.x >> 16);
        v[2] += bf2f(mv.y & 0xffffu); v[3] += bf2f(mv.y >> 16);
        v[4] += bf2f(mv.z & 0xffffu); v[5] += bf2f(mv.z >> 16);
        v[6] += bf2f(mv.w & 0xffffu); v[7] += bf2f(mv.w >> 16);
      }
      for (int k = 1; k < bc.y; ++k) {
        uint4 mv = ((const uint4*)(compact + (size_t)(bc.x + k) * 128))[l];
        v[0] += bf2f(mv.x & 0xffffu); v[1] += bf2f(mv.x >> 16);
        v[2] += bf2f(mv.y & 0xffffu); v[3] += bf2f(mv.y >> 16);
        v[4] += bf2f(mv.z & 0xffffu); v[5] += bf2f(mv.z >> 16);
        v[6] += bf2f(mv.w & 0xffffu); v[7] += bf2f(mv.w >> 16);
      }
      uint4 pk;
      pk.x = f2bf_pack(v[0], v[1]); pk.y = f2bf_pack(v[2], v[3]);
      pk.z = f2bf_pack(v[4], v[5]); pk.w = f2bf_pack(v[6], v[7]);
      ((uint4*)(outb + (size_t)j * 128))[l] = pk;
#pragma unroll
      for (int c = 0; c < 8; ++c) { s[c] += v[c]; q[c] += v[c] * v[c]; }
    }
  }

  // ---- stats reduce (reuse SH as float scratch; 256 recs x 17 = 17 KB) ----
  __syncthreads();
  float* red = (float*)SH;
  float* my = red + (grp * 16 + l) * 17;
#pragma unroll
  for (int c = 0; c < 8; ++c) { my[c] = s[c]; my[8 + c] = q[c]; }
  __syncthreads();
  {
    int c = tid & 127, stat = tid >> 7;       // stat 0=sum, 1=sumsq
    int lane16 = c >> 3, idx = (c & 7) + (stat ? 8 : 0);
    float v = 0.f;
#pragma unroll
    for (int g = 0; g < 16; ++g) v += red[(g * 16 + lane16) * 17 + idx];
    // sum[col] @ ws[col*16]; sumsq[col] @ ws[4096 + col*16]  (64B apart)
    unsafeAtomicAdd(&ws[stat * 4096 + c * 16], v);
  }
}

// normalize bf16 pre-norm buffer -> fp32 final out (reads padded stats)
__global__ __launch_bounds__(256) void norm_b(
    const unsigned short* __restrict__ outb, float* __restrict__ out,
    const float* __restrict__ ws, const float* __restrict__ gamma,
    const float* __restrict__ beta, int total8, float invN) {
  const int tid0 = blockIdx.x * 256 + threadIdx.x;
  const int c0 = (tid0 & 15) * 8;
  float sc[8], sh[8];
#pragma unroll
  for (int k = 0; k < 8; ++k) {
    float m = ws[(c0 + k) * 16] * invN;
    float var = ws[4096 + (c0 + k) * 16] * invN - m * m;
    sc[k] = gamma[c0 + k] * rsqrtf(var + EPS);
    sh[k] = beta[c0 + k] - m * sc[k];
  }
  for (int idx = tid0; idx < total8; idx += gridDim.x * 256) {
    uint4 v = *(const uint4*)(outb + (size_t)idx * 8);
    float f0 = bf2f(v.x & 0xffffu), f1 = bf2f(v.x >> 16);
    float f2 = bf2f(v.y & 0xffffu), f3 = bf2f(v.y >> 16);
    float f4 = bf2f(v.z & 0xffffu), f5 = bf2f(v.z >> 16);
    float f6 = bf2f(v.w & 0xffffu), f7 = bf2f(v.w >> 16);
    float4 o0, o1;
    o0.x = fmaxf(f0 * sc[0] + sh[0], 0.f);
    o0.y = fmaxf(f1 * sc[1] + sh[1], 0.f);
    o0.z = fmaxf(f2 * sc[2] + sh[2], 0.f);
    o0.w = fmaxf(f3 * sc[3] + sh[3], 0.f);
    o1.x = fmaxf(f4 * sc[4] + sh[4], 0.f);
    o1.y = fmaxf(f5 * sc[5] + sh[5], 0.f);
    o1.z = fmaxf(f6 * sc[6] + sh[6], 0.f);
    o1.w = fmaxf(f7 * sc[7] + sh[7], 0.f);
    *(float4*)(out + (size_t)idx * 8) = o0;
    *(float4*)(out + (size_t)idx * 8 + 4) = o1;
  }
}

// ===========================================================================
// FALLBACK PATHS (fp32 pipelines for small workspace)
// (unpadded ws stats layout: sum @ ws[0..128), sumsq @ ws[128..256))
// ===========================================================================

__global__ __launch_bounds__(256) void scatter_R(
    const int* __restrict__ S, int* __restrict__ R, int N, int pm) {
  const int p = blockIdx.x * 256 + threadIdx.x;
  const int i = blockIdx.y;
  if (p >= pm) return;
  const int idx = i * pm + p;
  const int s = S[idx];
  if (s < N) R[(size_t)s * 26 + i] = idx;
}

__global__ __launch_bounds__(256) void center_gemm(
    const float* __restrict__ f1, const float* __restrict__ f2,
    const float* __restrict__ W, const float* __restrict__ bias,
    float* __restrict__ out, int N, int N1) {
  __shared__ float fLDS[128 * 65];
  __shared__ float wLDS[32 * 128];
  const int tid = threadIdx.x;
  const int tx = tid & 15, ty = tid >> 4;
  const int row0 = blockIdx.x * 128;

  for (int k = 0; k < 8; ++k) {
    int flat4 = tid + k * 256;
    int row = flat4 >> 4, c4 = flat4 & 15;
    int grow = row0 + row;
    float4 v = make_float4(0.f, 0.f, 0.f, 0.f);
    if (grow < N) {
      const float* src = (grow < N1) ? (f1 + (size_t)grow * 64)
                                     : (f2 + (size_t)(grow - N1) * 64);
      v = *(const float4*)(src + c4 * 4);
    }
    int l = row * 65 + c4 * 4;
    fLDS[l + 0] = v.x; fLDS[l + 1] = v.y; fLDS[l + 2] = v.z; fLDS[l + 3] = v.w;
  }
  float acc[8][8];
#pragma unroll
  for (int r = 0; r < 8; ++r)
#pragma unroll
    for (int j = 0; j < 8; ++j) acc[r][j] = 0.f;
  for (int kk = 0; kk < 64; kk += 32) {
    __syncthreads();
    for (int k = 0; k < 4; ++k) {
      int flat4 = tid + k * 256;
      int c = flat4 >> 5, col4 = flat4 & 31;
      float4 v = *(const float4*)(W + (size_t)(kk + c) * 128 + col4 * 4);
      *(float4*)(wLDS + c * 128 + col4 * 4) = v;
    }
    __syncthreads();
#pragma unroll 4
    for (int c = 0; c < 32; ++c) {
      float a[8];
#pragma unroll
      for (int r = 0; r < 8; ++r) a[r] = fLDS[(ty * 8 + r) * 65 + kk + c];
      float4 b0 = *(const float4*)(wLDS + c * 128 + tx * 8);
      float4 b1 = *(const float4*)(wLDS + c * 128 + tx * 8 + 4);
      float b[8] = {b0.x, b0.y, b0.z, b0.w, b1.x, b1.y, b1.z, b1.w};
#pragma unroll
      for (int r = 0; r < 8; ++r)
#pragma unroll
        for (int j = 0; j < 8; ++j) acc[r][j] += a[r] * b[j];
    }
  }
  float4 bi0 = *(const float4*)(bias + tx * 8);
  float4 bi1 = *(const float4*)(bias + tx * 8 + 4);
#pragma unroll
  for (int r = 0; r < 8; ++r) {
    int grow = row0 + ty * 8 + r;
    if (grow < N) {
      float4 o0 = make_float4(acc[r][0] + bi0.x, acc[r][1] + bi0.y,
                              acc[r][2] + bi0.z, acc[r][3] + bi0.w);
      float4 o1 = make_float4(acc[r][4] + bi1.x, acc[r][5] + bi1.y,
                              acc[r][6] + bi1.z, acc[r][7] + bi1.w);
      float* dst = out + (size_t)grow * 128 + tx * 8;
      *(float4*)dst = o0;
      *(float4*)(dst + 4) = o1;
    }
  }
}

__global__ __launch_bounds__(256) void msg_gemm_buf(
    const float* __restrict__ f1, const float* __restrict__ f2,
    const float* __restrict__ W27, const int* __restrict__ G,
    const int* __restrict__ S, unsigned short* __restrict__ msgbuf,
    int N, int N1, int pm) {
  const int i = blockIdx.y;
  const int ktap = i + (i >= 13 ? 1 : 0);
  const float* W = W27 + (size_t)ktap * 64 * 128;
  const int* Gi = G + (size_t)i * pm;
  const int* Si = S + (size_t)i * pm;
  const int p0 = blockIdx.x * 128;
  if (Si[p0] >= N) return;
  __shared__ float fLDS[128 * 65];
  __shared__ float wLDS[32 * 128];
  const int tid = threadIdx.x;
  const int tx = tid & 15, ty = tid >> 4;
  for (int k = 0; k < 8; ++k) {
    int flat4 = tid + k * 256;
    int row = flat4 >> 4, c4 = flat4 & 15;
    int p = p0 + row;
    float4 v = make_float4(0.f, 0.f, 0.f, 0.f);
    if (p < pm) {
      int g = Gi[p];
      if (g < N) {
        const float* src = (g < N1) ? (f1 + (size_t)g * 64)
                                    : (f2 + (size_t)(g - N1) * 64);
        v = *(const float4*)(src + c4 * 4);
      }
    }
    int l = row * 65 + c4 * 4;
    fLDS[l + 0] = v.x; fLDS[l + 1] = v.y; fLDS[l + 2] = v.z; fLDS[l + 3] = v.w;
  }
  float acc[8][8];
#pragma unroll
  for (int r = 0; r < 8; ++r)
#pragma unroll
    for (int j = 0; j < 8; ++j) acc[r][j] = 0.f;
  for (int kk = 0; kk < 64; kk += 32) {
    __syncthreads();
    for (int k = 0; k < 4; ++k) {
      int flat4 = tid + k * 256;
      int c = flat4 >> 5, col4 = flat4 & 31;
      float4 v = *(const float4*)(W + (size_t)(kk + c) * 128 + col4 * 4);
      *(float4*)(wLDS + c * 128 + col4 * 4) = v;
    }
    __syncthreads();
#pragma unroll 4
    for (int c = 0; c < 32; ++c) {
      float a[8];
#pragma unroll
      for (int r = 0; r < 8; ++r) a[r] = fLDS[(ty * 8 + r) * 65 + kk + c];
      float4 b0 = *(const float4*)(wLDS + c * 128 + tx * 8);
      float4 b1 = *(const float4*)(wLDS + c * 128 + tx * 8 + 4);
      float b[8] = {b0.x, b0.y, b0.z, b0.w, b1.x, b1.y, b1.z, b1.w};
#pragma unroll
      for (int r = 0; r < 8; ++r)
#pragma unroll
        for (int j = 0; j < 8; ++j) acc[r][j] += a[r] * b[j];
    }
  }
#pragma unroll
  for (int r = 0; r < 8; ++r) {
    int p = p0 + ty * 8 + r;
    if (p < pm) {
      uint4 pk;
      pk.x = f2bf_pack(acc[r][0], acc[r][1]);
      pk.y = f2bf_pack(acc[r][2], acc[r][3]);
      pk.z = f2bf_pack(acc[r][4], acc[r][5]);
      pk.w = f2bf_pack(acc[r][6], acc[r][7]);
      *(uint4*)(msgbuf + ((size_t)i * pm + p) * 128 + tx * 8) = pk;
    }
  }
}

__global__ __launch_bounds__(256) void msg_gemm(
    const float* __restrict__ f1, const float* __restrict__ f2,
    const float* __restrict__ W27, const int* __restrict__ G,
    const int* __restrict__ S, float* __restrict__ out,
    int N, int N1, int pm) {
  const int i = blockIdx.y;
  const int ktap = i + (i >= 13 ? 1 : 0);
  const float* W = W27 + (size_t)ktap * 64 * 128;
  const int* Gi = G + (size_t)i * pm;
  const int* Si = S + (size_t)i * pm;
  const int p0 = blockIdx.x * 128;
  if (Si[p0] >= N) return;
  __shared__ float fLDS[128 * 65];
  __shared__ float wLDS[32 * 128];
  const int tid = threadIdx.x;
  const int tx = tid & 15, ty = tid >> 4;
  for (int k = 0; k < 8; ++k) {
    int flat4 = tid + k * 256;
    int row = flat4 >> 4, c4 = flat4 & 15;
    int p = p0 + row;
    float4 v = make_float4(0.f, 0.f, 0.f, 0.f);
    if (p < pm) {
      int g = Gi[p];
      if (g < N) {
        const float* src = (g < N1) ? (f1 + (size_t)g * 64)
                                    : (f2 + (size_t)(g - N1) * 64);
        v = *(const float4*)(src + c4 * 4);
      }
    }
    int l = row * 65 + c4 * 4;
    fLDS[l + 0] = v.x; fLDS[l + 1] = v.y; fLDS[l + 2] = v.z; fLDS[l + 3] = v.w;
  }
  float acc[8][8];
#pragma unroll
  for (int r = 0; r < 8; ++r)
#pragma unroll
    for (int j = 0; j < 8; ++j) acc[r][j] = 0.f;
  for (int kk = 0; kk < 64; kk += 32) {
    __syncthreads();
    for (int k = 0; k < 4; ++k) {
      int flat4 = tid + k * 256;
      int c = flat4 >> 5, col4 = flat4 & 31;
      float4 v = *(const float4*)(W + (size_t)(kk + c) * 128 + col4 * 4);
      *(float4*)(wLDS + c * 128 + col4 * 4) = v;
    }
    __syncthreads();
#pragma unroll 4
    for (int c = 0; c < 32; ++c) {
      float a[8];
#pragma unroll
      for (int r = 0; r < 8; ++r) a[r] = fLDS[(ty * 8 + r) * 65 + kk + c];
      float4 b0 = *(const float4*)(wLDS + c * 128 + tx * 8);
      float4 b1 = *(const float4*)(wLDS + c * 128 + tx * 8 + 4);
      float b[8] = {b0.x, b0.y, b0.z, b0.w, b1.x, b1.y, b1.z, b1.w};
#pragma unroll
      for (int r = 0; r < 8; ++r)
#pragma unroll
        for (int j = 0; j < 8; ++j) acc[r][j] += a[r] * b[j];
    }
  }
#pragma unroll
  for (int r = 0; r < 8; ++r) {
    int p = p0 + ty * 8 + r;
    if (p < pm) {
      int s = Si[p];
      if (s < N) {
        float* dst = out + (size_t)s * 128 + tx * 8;
#pragma unroll
        for (int j = 0; j < 8; ++j) unsafeAtomicAdd(dst + j, acc[r][j]);
      }
    }
  }
}

__global__ __launch_bounds__(256) void combine_stats(
    float* __restrict__ out, const int* __restrict__ R,
    const unsigned short* __restrict__ msgbuf, float* __restrict__ ws,
    int N) {
  const int tid = threadIdx.x;
  const int grp = tid >> 5, l = tid & 31;
  const int base = tid & 32;
  float4 s = make_float4(0.f, 0.f, 0.f, 0.f);
  float4 q = make_float4(0.f, 0.f, 0.f, 0.f);
  for (int j = blockIdx.x * 8 + grp; j < N; j += gridDim.x * 8) {
    float4 v = ((const float4*)(out + (size_t)j * 128))[l];
    int r = (l < 26) ? R[(size_t)j * 26 + l] : -1;
    unsigned long long bal = __ballot(r >= 0);
    unsigned mym = (unsigned)((bal >> base) & 0x3FFFFFFull);
    const bool any = (mym != 0);
    while (mym) {
      int b = __builtin_ctz(mym);
      mym &= mym - 1;
      int ptr = __shfl(r, base + b, 64);
      uint2 mv = ((const uint2*)(msgbuf + (size_t)ptr * 128))[l];
      v.x += bf2f(mv.x & 0xffffu);
      v.y += bf2f(mv.x >> 16);
      v.z += bf2f(mv.y & 0xffffu);
      v.w += bf2f(mv.y >> 16);
    }
    if (any) ((float4*)(out + (size_t)j * 128))[l] = v;
    s.x += v.x; s.y += v.y; s.z += v.z; s.w += v.w;
    q.x += v.x * v.x; q.y += v.y * v.y; q.z += v.z * v.z; q.w += v.w * v.w;
  }
  __shared__ float red[8 * 32 * 8];
  float* my = red + (grp * 32 + l) * 8;
  my[0] = s.x; my[1] = s.y; my[2] = s.z; my[3] = s.w;
  my[4] = q.x; my[5] = q.y; my[6] = q.z; my[7] = q.w;
  __syncthreads();
  {
    int c4 = tid & 31, j = tid >> 5;
    float v = 0.f;
#pragma unroll
    for (int g = 0; g < 8; ++g) v += red[(g * 32 + c4) * 8 + j];
    int col = c4 * 4 + (j & 3);
    unsafeAtomicAdd(&ws[col + (j >> 2) * 128], v);
  }
}

__global__ __launch_bounds__(256) void stats_kernel(
    const float* __restrict__ out, float* __restrict__ ws, int total4) {
  const int tid = threadIdx.x;
  float4 s = make_float4(0.f, 0.f, 0.f, 0.f);
  float4 q = make_float4(0.f, 0.f, 0.f, 0.f);
  const float4* o4 = (const float4*)out;
  for (int idx = blockIdx.x * 256 + tid; idx < total4; idx += gridDim.x * 256) {
    float4 v = o4[idx];
    s.x += v.x; s.y += v.y; s.z += v.z; s.w += v.w;
    q.x += v.x * v.x; q.y += v.y * v.y; q.z += v.z * v.z; q.w += v.w * v.w;
  }
  __shared__ float red[8 * 32 * 8];
  const int col4 = tid & 31, grpq = tid >> 5;
  float* my = red + (grpq * 32 + col4) * 8;
  my[0] = s.x; my[1] = s.y; my[2] = s.z; my[3] = s.w;
  my[4] = q.x; my[5] = q.y; my[6] = q.z; my[7] = q.w;
  __syncthreads();
  {
    int c4 = tid & 31, j = tid >> 5;
    float v = 0.f;
#pragma unroll
    for (int g = 0; g < 8; ++g) v += red[(g * 32 + c4) * 8 + j];
    int col = c4 * 4 + (j & 3);
    unsafeAtomicAdd(&ws[col + (j >> 2) * 128], v);
  }
}

__global__ __launch_bounds__(256) void norm_kernel(
    float* __restrict__ out, const float* __restrict__ ws,
    const float* __restrict__ gamma, const float* __restrict__ beta,
    int total4, float invN) {
  const int tid = threadIdx.x;
  const int c4 = tid & 31;
  float4 s = ((const float4*)ws)[c4];
  float4 q = ((const float4*)ws)[32 + c4];
  float4 g = ((const float4*)gamma)[c4];
  float4 b = ((const float4*)beta)[c4];
  float m0 = s.x * invN, m1 = s.y * invN, m2 = s.z * invN, m3 = s.w * invN;
  float sc0 = g.x * rsqrtf(q.x * invN - m0 * m0 + EPS);
  float sc1 = g.y * rsqrtf(q.y * invN - m1 * m1 + EPS);
  float sc2 = g.z * rsqrtf(q.z * invN - m2 * m2 + EPS);
  float sc3 = g.w * rsqrtf(q.w * invN - m3 * m3 + EPS);
  float sh0 = b.x - m0 * sc0, sh1 = b.y - m1 * sc1;
  float sh2 = b.z - m2 * sc2, sh3 = b.w - m3 * sc3;
  float4* o4 = (float4*)out;
  for (int idx = blockIdx.x * 256 + tid; idx < total4; idx += gridDim.x * 256) {
    float4 v = o4[idx];
    v.x = fmaxf(v.x * sc0 + sh0, 0.f);
    v.y = fmaxf(v.y * sc1 + sh1, 0.f);
    v.z = fmaxf(v.z * sc2 + sh2, 0.f);
    v.w = fmaxf(v.w * sc3 + sh3, 0.f);
    o4[idx] = v;
  }
}

// ===========================================================================
extern "C" void kernel_launch(void* const* d_in, const int* in_sizes, int n_in,
                              void* d_out, int out_size, void* d_ws, size_t ws_size,
                              hipStream_t stream) {
  const float* f1 = (const float*)d_in[0];
  const float* f2 = (const float*)d_in[1];
  const float* W = (const float*)d_in[2];
  const float* bias = (const float*)d_in[3];
  const float* gamma = (const float*)d_in[4];
  const float* beta = (const float*)d_in[5];
  const int* G = (const int*)d_in[6];
  const int* S = (const int*)d_in[7];
  const int N1 = in_sizes[0] / 64;
  const int N2 = in_sizes[1] / 64;
  const int N = N1 + N2;
  const int pm = in_sizes[6] / 26;
  float* out = (float*)d_out;
  float* ws = (float*)d_ws;

  const size_t AL = 255;
  // full path layout (padded stats + gtot in first 32 KB; cnt right after
  // so one memset covers both)
  const size_t offC = 32768;                       // cnt: N ints
  const size_t Cb = (size_t)N * 4;
  const size_t offBC = (offC + Cb + AL) & ~AL;     // BC: N int2
  const size_t BCb = (size_t)N * 8;
  const size_t offSL = (offBC + BCb + AL) & ~AL;   // SL: 26*pm bytes
  const size_t SLb = (size_t)26 * pm;
  const size_t offF = (offSL + SLb + AL) & ~AL;    // fbuf: (N+1) x 64 bf16
  const size_t Fb = (size_t)(N + 1) * 64 * 2;
  const size_t offW = (offF + Fb + AL) & ~AL;
  const size_t Wbyt = (size_t)27 * 128 * 64 * 2;
  const size_t offM = (offW + Wbyt + AL) & ~AL;
  const size_t Mb = (size_t)26 * pm * 128 * 2;     // compact (messages only)
  const size_t offO = (offM + Mb + AL) & ~AL;
  const size_t Ob = (size_t)N * 128 * 2;
  const bool full = ws_size >= offO + Ob;

  // fp32 fallback layout (unpadded stats: 1 KB)
  const size_t Rb = (size_t)N * 26 * 4;
  const size_t offR2 = 1024;
  const size_t offM2 = (offR2 + Rb + AL) & ~AL;
  const bool fast2 = ws_size >= offM2 + Mb;

  if (full) {
    int* cnt = (int*)((char*)d_ws + offC);
    int2* BC = (int2*)((char*)d_ws + offBC);
    unsigned char* SLp = (unsigned char*)((char*)d_ws + offSL);
    unsigned short* fbuf = (unsigned short*)((char*)d_ws + offF);
    unsigned short* Wb = (unsigned short*)((char*)d_ws + offW);
    unsigned short* compact = (unsigned short*)((char*)d_ws + offM);
    unsigned short* outb = (unsigned short*)((char*)d_ws + offO);
    int* gtot = (int*)((char*)d_ws + 28672);  // inside zeroed stats block

    const int wblocks = (27 * 128 * 64) / 256;     // 864
    const int fblocks = ((N + 1) * 8 + 255) / 256;
    const int cpb256 = (pm + 255) / 256;
    const int cpb128 = (pm + 127) / 128;
    const int cblocks = (N + 127) / 128;

    (void)hipMemsetAsync(ws, 0, offC + Cb, stream);  // stats + gtot + cnt
    prep<<<wblocks + fblocks + 26 * cpb256, 256, 0, stream>>>(
        W, Wb, f1, f2, fbuf, S, SLp, cnt, N, N1, pm, wblocks, fblocks,
        cpb256);
    prefix_base<<<(N + 1023) / 1024, 256, 0, stream>>>(cnt, BC, gtot, N);
    msg_mfma_c<<<dim3(cpb128, 26), 256, 0, stream>>>(
        fbuf, Wb, G, S, BC, SLp, compact, N, pm);
    center_combine<<<cblocks, 256, 0, stream>>>(
        fbuf, Wb + (size_t)13 * 128 * 64, bias, BC, compact, outb, ws, N);
    norm_b<<<2048, 256, 0, stream>>>(outb, out, ws, gamma, beta, N * 16,
                                     1.0f / N);
  } else if (fast2) {
    int* R = (int*)((char*)d_ws + offR2);
    unsigned short* msgbuf = (unsigned short*)((char*)d_ws + offM2);
    (void)hipMemsetAsync(ws, 0, 256 * sizeof(float), stream);
    (void)hipMemsetAsync(R, 0xFF, Rb, stream);
    center_gemm<<<(N + 127) / 128, 256, 0, stream>>>(
        f1, f2, W + (size_t)13 * 64 * 128, bias, out, N, N1);
    scatter_R<<<dim3((pm + 255) / 256, 26), 256, 0, stream>>>(S, R, N, pm);
    msg_gemm_buf<<<dim3((pm + 127) / 128, 26), 256, 0, stream>>>(
        f1, f2, W, G, S, msgbuf, N, N1, pm);
    combine_stats<<<1024, 256, 0, stream>>>(out, R, msgbuf, ws, N);
    norm_kernel<<<2048, 256, 0, stream>>>(out, ws, gamma, beta, N * 32,
                                          1.0f / N);
  } else {
    (void)hipMemsetAsync(ws, 0, 256 * sizeof(float), stream);
    center_gemm<<<(N + 127) / 128, 256, 0, stream>>>(
        f1, f2, W + (size_t)13 * 64 * 128, bias, out, N, N1);
    msg_gemm<<<dim3((pm + 127) / 128, 26), 256, 0, stream>>>(
        f1, f2, W, G, S, out, N, N1, pm);
    stats_kernel<<<1024, 256, 0, stream>>>(out, ws, N * 32);
    norm_kernel<<<2048, 256, 0, stream>>>(out, ws, gamma, beta, N * 32,
                                          1.0f / N);
  }
}

// Round 10
// 323.836 us; speedup vs baseline: 1.0004x; 1.0004x over previous
//
#include <hip/hip_runtime.h>

#define EPS 1e-3f

typedef __attribute__((ext_vector_type(8))) short bf8_t;   // 8 bf16 (4 VGPRs)
typedef __attribute__((ext_vector_type(4))) float f32x4;   // MFMA acc

static __device__ __forceinline__ unsigned f2bf_pack(float a, float b) {
  union { float f; unsigned u; } ca, cb;
  ca.f = a; cb.f = b;
  unsigned ra = (ca.u + 0x7FFFu + ((ca.u >> 16) & 1u)) >> 16;
  unsigned rb = (cb.u + 0x7FFFu + ((cb.u >> 16) & 1u)) >> 16;
  return ra | (rb << 16);
}
static __device__ __forceinline__ unsigned short f2bf1(float x) {
  union { float f; unsigned u; } c; c.f = x;
  return (unsigned short)((c.u + 0x7FFFu + ((c.u >> 16) & 1u)) >> 16);
}
static __device__ __forceinline__ float bf2f(unsigned bits16) {
  union { unsigned u; float f; } c;
  c.u = bits16 << 16;
  return c.f;
}

// ===========================================================================
// FULL (MFMA + bf16) PATH — destination-compacted messages (msgs only),
// center fused with combine+stats (128-row tile, NO LDS park: center written
// to outb, combined via L2-hot re-read).
// ws layout: [0,32KB) padded stats (sum[c] @ c*16 floats, sumsq @ 4096+c*16,
//            gtot @ byte 28672) | cnt (@32KB, one memset covers both) | BC |
//            SL | fbuf | Wb | compact | outb
// Dispatches: memset | prep | prefix | msg | center_combine | norm  (6)
// ===========================================================================

// fused: Wb transpose-convert | feats fp32->bf16 fbuf | per-(tap,p) slot grab
__global__ __launch_bounds__(256) void prep(
    const float* __restrict__ W, unsigned short* __restrict__ Wb,
    const float* __restrict__ f1, const float* __restrict__ f2,
    unsigned short* __restrict__ fbuf,
    const int* __restrict__ S, unsigned char* __restrict__ SL,
    int* __restrict__ cnt, int N, int N1, int pm,
    int wblocks, int fblocks, int cpb) {
  const int bid = blockIdx.x;
  if (bid < wblocks) {
    // W[27][64][128] fp32 -> Wb[27][128][64] bf16 (27*128*64 = 864 blocks)
    int idx = bid * 256 + threadIdx.x;
    int k = idx & 63, n = (idx >> 6) & 127, t = idx >> 13;
    Wb[idx] = f2bf1(W[((size_t)t * 64 + k) * 128 + n]);
  } else if (bid < wblocks + fblocks) {
    // feats (f1|f2) fp32 -> fbuf bf16, (N+1) rows x 64, row N = zeros
    int idx = (bid - wblocks) * 256 + threadIdx.x;  // (N+1)*8 segs of 8
    if (idx >= (N + 1) * 8) return;
    int row = idx >> 3, seg = idx & 7;
    uint4 o = make_uint4(0, 0, 0, 0);
    if (row < N) {
      const float* src = (row < N1) ? (f1 + (size_t)row * 64)
                                    : (f2 + (size_t)(row - N1) * 64);
      float4 v0 = *(const float4*)(src + seg * 8);
      float4 v1 = *(const float4*)(src + seg * 8 + 4);
      o.x = f2bf_pack(v0.x, v0.y); o.y = f2bf_pack(v0.z, v0.w);
      o.z = f2bf_pack(v1.x, v1.y); o.w = f2bf_pack(v1.z, v1.w);
    }
    *(uint4*)(fbuf + (size_t)idx * 8) = o;
  } else {
    int b = bid - wblocks - fblocks;
    int tap = b / cpb;
    int p = (b - tap * cpb) * 256 + threadIdx.x;
    if (p >= pm) return;
    const int idx = tap * pm + p;
    const int s = S[idx];
    if (s < N) SL[idx] = (unsigned char)atomicAdd(&cnt[s], 1);  // max 26/row
  }
}

// exclusive prefix over cnt -> BC[j] = (base, cnt). Block order arbitrary
// (atomic chunk base) but stored, hence consistent for all consumers.
__global__ __launch_bounds__(256) void prefix_base(
    const int* __restrict__ cnt, int2* __restrict__ BC,
    int* __restrict__ gtot, int N) {
  const int t = threadIdx.x;
  const int j0 = blockIdx.x * 1024 + t * 4;
  int c0 = 0, c1 = 0, c2 = 0, c3 = 0;
  if (j0 + 3 < N) {
    int4 c = *(const int4*)(cnt + j0);
    c0 = c.x; c1 = c.y; c2 = c.z; c3 = c.w;
  } else {
    if (j0 < N) c0 = cnt[j0];
    if (j0 + 1 < N) c1 = cnt[j0 + 1];
    if (j0 + 2 < N) c2 = cnt[j0 + 2];
  }
  const int tsum = c0 + c1 + c2 + c3;
  int incl = tsum;
#pragma unroll
  for (int off = 1; off < 64; off <<= 1) {
    int u = __shfl_up(incl, off, 64);
    if ((t & 63) >= off) incl += u;
  }
  __shared__ int wsum[4];
  if ((t & 63) == 63) wsum[t >> 6] = incl;
  __syncthreads();
  if (t == 0) {
    int w0 = wsum[0], w1 = wsum[1], w2 = wsum[2], w3 = wsum[3];
    int gb = atomicAdd(gtot, w0 + w1 + w2 + w3);
    wsum[0] = gb; wsum[1] = gb + w0;
    wsum[2] = gb + w0 + w1; wsum[3] = gb + w0 + w1 + w2;
  }
  __syncthreads();
  const int excl = wsum[t >> 6] + incl - tsum;
  if (j0 < N) BC[j0] = make_int2(excl, c0);
  if (j0 + 1 < N) BC[j0 + 1] = make_int2(excl + c0, c1);
  if (j0 + 2 < N) BC[j0 + 2] = make_int2(excl + c0 + c1, c2);
  if (j0 + 3 < N) BC[j0 + 3] = make_int2(excl + c0 + c1 + c2, c3);
}

// 26 neighbor taps -> compact[(BC[s].x + SL[tap,p])*128 + col]
__global__ __launch_bounds__(256) void msg_mfma_c(
    const unsigned short* __restrict__ fbuf,
    const unsigned short* __restrict__ Wb,
    const int* __restrict__ G, const int* __restrict__ S,
    const int2* __restrict__ BC, const unsigned char* __restrict__ SL,
    unsigned short* __restrict__ compact, int N, int pm) {
  const int tap = blockIdx.y;                 // tap index (0..25)
  const int ktap = tap + (tap >= 13 ? 1 : 0);
  const unsigned short* Wt = Wb + (size_t)ktap * 128 * 64;
  const int* Gi = G + (size_t)tap * pm;
  const int* Si = S + (size_t)tap * pm;
  const int p0 = blockIdx.x * 128;
  if (Gi[p0] >= N) return;  // fully-padded tail block (padding G == N)

  __shared__ unsigned short A[128 * 64];
  __shared__ int g_lds[128];
  __shared__ int d_lds[128];
  const int tid = threadIdx.x;
  if (tid < 128) {
    int p = p0 + tid;
    int g = N, d = -1;
    if (p < pm) {
      g = Gi[p];
      int s = Si[p];
      if (s < N) d = BC[s].x + (int)SL[(size_t)tap * pm + p];
    }
    g_lds[tid] = g;
    d_lds[tid] = d;
  }
  __syncthreads();

#pragma unroll
  for (int it = 0; it < 4; ++it) {
    int flat = it * 256 + tid;       // 128 rows x 8 segs of 8 bf16
    int r = flat >> 3, qs = flat & 7;
    int g = g_lds[r];                 // g in [0,N]; row N is zeros
    uint4 v = *(const uint4*)(fbuf + (size_t)g * 64 + qs * 8);
    int rt = r >> 4, m = r & 15, c = qs >> 2, qq = qs & 3;
    *(uint4*)(A + ((rt * 2 + c) * 64 + qq * 16 + m) * 8) = v;
  }
  __syncthreads();

  const int wave = tid >> 6, lane = tid & 63;
  const int ncol = lane & 15, q2 = lane >> 4;
  bf8_t Bf[2][2];
#pragma unroll
  for (int ct = 0; ct < 2; ++ct) {
    int col = wave * 32 + ct * 16 + ncol;
#pragma unroll
    for (int c = 0; c < 2; ++c)
      Bf[ct][c] = *(const bf8_t*)(Wt + (size_t)col * 64 + c * 32 + q2 * 8);
  }
  f32x4 acc[8][2];
#pragma unroll
  for (int rt = 0; rt < 8; ++rt)
#pragma unroll
    for (int ct = 0; ct < 2; ++ct) acc[rt][ct] = (f32x4){0.f, 0.f, 0.f, 0.f};

#pragma unroll
  for (int rt = 0; rt < 8; ++rt) {
    bf8_t a0 = *(const bf8_t*)(A + ((rt * 2 + 0) * 64 + lane) * 8);
    bf8_t a1 = *(const bf8_t*)(A + ((rt * 2 + 1) * 64 + lane) * 8);
#pragma unroll
    for (int ct = 0; ct < 2; ++ct) {
      acc[rt][ct] = __builtin_amdgcn_mfma_f32_16x16x32_bf16(a0, Bf[ct][0], acc[rt][ct], 0, 0, 0);
      acc[rt][ct] = __builtin_amdgcn_mfma_f32_16x16x32_bf16(a1, Bf[ct][1], acc[rt][ct], 0, 0, 0);
    }
  }

#pragma unroll
  for (int rt = 0; rt < 8; ++rt) {
    int dl[4];
#pragma unroll
    for (int e = 0; e < 4; ++e) dl[e] = d_lds[rt * 16 + q2 * 4 + e];
#pragma unroll
    for (int ct = 0; ct < 2; ++ct) {
      int col = wave * 32 + ct * 16 + ncol;
#pragma unroll
      for (int e = 0; e < 4; ++e)
        if (dl[e] >= 0)
          compact[(size_t)dl[e] * 128 + col] = f2bf1(acc[rt][ct][e]);
    }
  }
}

// center MFMA + coalesced message combine + stats, one kernel (128-row tile).
// Phase 1: stage 128 center rows (bf16) into SH[:16K], MFMA (8 rt).
// Phase 2: write bf16(center+bias) DIRECTLY to outb (no LDS park);
//          __syncthreads drains vmcnt -> block-coherent.
// Phase 3: 16 x 16-lane groups, 8 rows each: re-read own outb rows
//          (L1/L2-hot, uint4/lane) + contiguous compact message rows;
//          rewrite only rows with messages; stats for all rows.
// LDS: 17408 B (A staging 16 KB, stats scratch 17 KB, time-shared).
__global__ __launch_bounds__(256) void center_combine(
    const unsigned short* __restrict__ fbuf,
    const unsigned short* __restrict__ Wb13, const float* __restrict__ bias,
    const int2* __restrict__ BC, const unsigned short* __restrict__ compact,
    unsigned short* __restrict__ outb, float* __restrict__ ws, int N) {
  __shared__ unsigned short SH[128 * 68];  // 17408 B
  __shared__ int2 bc_lds[128];
  const int tid = threadIdx.x;
  const int row0 = blockIdx.x * 128;

  if (tid < 128) {
    int j = row0 + tid;
    bc_lds[tid] = (j < N) ? BC[j] : make_int2(0, 0);
  }

  // ---- stage A (center rows, sequential fbuf reads): 128 rows x 8 segs ----
#pragma unroll
  for (int it = 0; it < 4; ++it) {
    int flat = it * 256 + tid;
    int r = flat >> 3, qs = flat & 7;
    int g = row0 + r; if (g >= N) g = N;  // row N is zeros
    uint4 v = *(const uint4*)(fbuf + (size_t)g * 64 + qs * 8);
    int rt = r >> 4, m = r & 15, c = qs >> 2, qq = qs & 3;
    *(uint4*)(SH + ((rt * 2 + c) * 64 + qq * 16 + m) * 8) = v;
  }
  __syncthreads();

  const int wave = tid >> 6, lane = tid & 63;
  const int ncol = lane & 15, q2 = lane >> 4;
  bf8_t Bf[2][2];
  float bs[2];
#pragma unroll
  for (int ct = 0; ct < 2; ++ct) {
    int col = wave * 32 + ct * 16 + ncol;
    bs[ct] = bias[col];
#pragma unroll
    for (int c = 0; c < 2; ++c)
      Bf[ct][c] = *(const bf8_t*)(Wb13 + (size_t)col * 64 + c * 32 + q2 * 8);
  }
  f32x4 acc[8][2];
#pragma unroll
  for (int rt = 0; rt < 8; ++rt)
#pragma unroll
    for (int ct = 0; ct < 2; ++ct) acc[rt][ct] = (f32x4){0.f, 0.f, 0.f, 0.f};

#pragma unroll
  for (int rt = 0; rt < 8; ++rt) {
    bf8_t a0 = *(const bf8_t*)(SH + ((rt * 2 + 0) * 64 + lane) * 8);
    bf8_t a1 = *(const bf8_t*)(SH + ((rt * 2 + 1) * 64 + lane) * 8);
#pragma unroll
    for (int ct = 0; ct < 2; ++ct) {
      acc[rt][ct] = __builtin_amdgcn_mfma_f32_16x16x32_bf16(a0, Bf[ct][0], acc[rt][ct], 0, 0, 0);
      acc[rt][ct] = __builtin_amdgcn_mfma_f32_16x16x32_bf16(a1, Bf[ct][1], acc[rt][ct], 0, 0, 0);
    }
  }

  // ---- write bf16(center+bias) directly to outb (acc layout) ----
#pragma unroll
  for (int rt = 0; rt < 8; ++rt)
#pragma unroll
    for (int ct = 0; ct < 2; ++ct) {
      int col = wave * 32 + ct * 16 + ncol;
#pragma unroll
      for (int e = 0; e < 4; ++e) {
        int row = row0 + rt * 16 + q2 * 4 + e;
        if (row < N)
          outb[(size_t)row * 128 + col] = f2bf1(acc[rt][ct][e] + bs[ct]);
      }
    }
  __syncthreads();  // drains vmcnt: outb writes visible block-wide

  // ---- coalesced combine: 16 groups x 8 rows, uint4 (16 B) per lane ----
  const int grp = tid >> 4, l = tid & 15;
  float s[8], q[8];
#pragma unroll
  for (int c = 0; c < 8; ++c) { s[c] = 0.f; q[c] = 0.f; }
#pragma unroll 2
  for (int i = 0; i < 8; ++i) {
    int r = grp * 8 + i;
    int j = row0 + r;
    if (j < N) {
      int2 bc = bc_lds[r];  // uniform across group -> broadcast
      uint4 cv = ((const uint4*)(outb + (size_t)j * 128))[l];  // L2-hot
      float v[8];
      v[0] = bf2f(cv.x & 0xffffu); v[1] = bf2f(cv.x >> 16);
      v[2] = bf2f(cv.y & 0xffffu); v[3] = bf2f(cv.y >> 16);
      v[4] = bf2f(cv.z & 0xffffu); v[5] = bf2f(cv.z >> 16);
      v[6] = bf2f(cv.w & 0xffffu); v[7] = bf2f(cv.w >> 16);
      for (int k = 0; k < bc.y; ++k) {
        uint4 mv = ((const uint4*)(compact + (size_t)(bc.x + k) * 128))[l];
        v[0] += bf2f(mv.x & 0xffffu); v[1] += bf2f(mv.x >> 16);
        v[2] += bf2f(mv.y & 0xffffu); v[3] += bf2f(mv.y >> 16);
        v[4] += bf2f(mv.z & 0xffffu); v[5] += bf2f(mv.z >> 16);
        v[6] += bf2f(mv.w & 0xffffu); v[7] += bf2f(mv.w >> 16);
      }
      if (bc.y) {
        uint4 pk;
        pk.x = f2bf_pack(v[0], v[1]); pk.y = f2bf_pack(v[2], v[3]);
        pk.z = f2bf_pack(v[4], v[5]); pk.w = f2bf_pack(v[6], v[7]);
        ((uint4*)(outb + (size_t)j * 128))[l] = pk;
      }
#pragma unroll
      for (int c = 0; c < 8; ++c) { s[c] += v[c]; q[c] += v[c] * v[c]; }
    }
  }

  // ---- stats reduce (reuse SH as float scratch; 256 recs x 17 = 17 KB) ----
  __syncthreads();
  float* red = (float*)SH;
  float* my = red + (grp * 16 + l) * 17;
#pragma unroll
  for (int c = 0; c < 8; ++c) { my[c] = s[c]; my[8 + c] = q[c]; }
  __syncthreads();
  {
    int c = tid & 127, stat = tid >> 7;       // stat 0=sum, 1=sumsq
    int lane16 = c >> 3, idx = (c & 7) + (stat ? 8 : 0);
    float v = 0.f;
#pragma unroll
    for (int g = 0; g < 16; ++g) v += red[(g * 16 + lane16) * 17 + idx];
    // sum[col] @ ws[col*16]; sumsq[col] @ ws[4096 + col*16]  (64B apart)
    unsafeAtomicAdd(&ws[stat * 4096 + c * 16], v);
  }
}

// normalize bf16 pre-norm buffer -> fp32 final out (reads padded stats)
__global__ __launch_bounds__(256) void norm_b(
    const unsigned short* __restrict__ outb, float* __restrict__ out,
    const float* __restrict__ ws, const float* __restrict__ gamma,
    const float* __restrict__ beta, int total8, float invN) {
  const int tid0 = blockIdx.x * 256 + threadIdx.x;
  const int c0 = (tid0 & 15) * 8;
  float sc[8], sh[8];
#pragma unroll
  for (int k = 0; k < 8; ++k) {
    float m = ws[(c0 + k) * 16] * invN;
    float var = ws[4096 + (c0 + k) * 16] * invN - m * m;
    sc[k] = gamma[c0 + k] * rsqrtf(var + EPS);
    sh[k] = beta[c0 + k] - m * sc[k];
  }
  for (int idx = tid0; idx < total8; idx += gridDim.x * 256) {
    uint4 v = *(const uint4*)(outb + (size_t)idx * 8);
    float f0 = bf2f(v.x & 0xffffu), f1 = bf2f(v.x >> 16);
    float f2 = bf2f(v.y & 0xffffu), f3 = bf2f(v.y >> 16);
    float f4 = bf2f(v.z & 0xffffu), f5 = bf2f(v.z >> 16);
    float f6 = bf2f(v.w & 0xffffu), f7 = bf2f(v.w >> 16);
    float4 o0, o1;
    o0.x = fmaxf(f0 * sc[0] + sh[0], 0.f);
    o0.y = fmaxf(f1 * sc[1] + sh[1], 0.f);
    o0.z = fmaxf(f2 * sc[2] + sh[2], 0.f);
    o0.w = fmaxf(f3 * sc[3] + sh[3], 0.f);
    o1.x = fmaxf(f4 * sc[4] + sh[4], 0.f);
    o1.y = fmaxf(f5 * sc[5] + sh[5], 0.f);
    o1.z = fmaxf(f6 * sc[6] + sh[6], 0.f);
    o1.w = fmaxf(f7 * sc[7] + sh[7], 0.f);
    *(float4*)(out + (size_t)idx * 8) = o0;
    *(float4*)(out + (size_t)idx * 8 + 4) = o1;
  }
}

// ===========================================================================
// FALLBACK PATHS (fp32 pipelines for small workspace)
// (unpadded ws stats layout: sum @ ws[0..128), sumsq @ ws[128..256))
// ===========================================================================

__global__ __launch_bounds__(256) void scatter_R(
    const int* __restrict__ S, int* __restrict__ R, int N, int pm) {
  const int p = blockIdx.x * 256 + threadIdx.x;
  const int i = blockIdx.y;
  if (p >= pm) return;
  const int idx = i * pm + p;
  const int s = S[idx];
  if (s < N) R[(size_t)s * 26 + i] = idx;
}

__global__ __launch_bounds__(256) void center_gemm(
    const float* __restrict__ f1, const float* __restrict__ f2,
    const float* __restrict__ W, const float* __restrict__ bias,
    float* __restrict__ out, int N, int N1) {
  __shared__ float fLDS[128 * 65];
  __shared__ float wLDS[32 * 128];
  const int tid = threadIdx.x;
  const int tx = tid & 15, ty = tid >> 4;
  const int row0 = blockIdx.x * 128;

  for (int k = 0; k < 8; ++k) {
    int flat4 = tid + k * 256;
    int row = flat4 >> 4, c4 = flat4 & 15;
    int grow = row0 + row;
    float4 v = make_float4(0.f, 0.f, 0.f, 0.f);
    if (grow < N) {
      const float* src = (grow < N1) ? (f1 + (size_t)grow * 64)
                                     : (f2 + (size_t)(grow - N1) * 64);
      v = *(const float4*)(src + c4 * 4);
    }
    int l = row * 65 + c4 * 4;
    fLDS[l + 0] = v.x; fLDS[l + 1] = v.y; fLDS[l + 2] = v.z; fLDS[l + 3] = v.w;
  }
  float acc[8][8];
#pragma unroll
  for (int r = 0; r < 8; ++r)
#pragma unroll
    for (int j = 0; j < 8; ++j) acc[r][j] = 0.f;
  for (int kk = 0; kk < 64; kk += 32) {
    __syncthreads();
    for (int k = 0; k < 4; ++k) {
      int flat4 = tid + k * 256;
      int c = flat4 >> 5, col4 = flat4 & 31;
      float4 v = *(const float4*)(W + (size_t)(kk + c) * 128 + col4 * 4);
      *(float4*)(wLDS + c * 128 + col4 * 4) = v;
    }
    __syncthreads();
#pragma unroll 4
    for (int c = 0; c < 32; ++c) {
      float a[8];
#pragma unroll
      for (int r = 0; r < 8; ++r) a[r] = fLDS[(ty * 8 + r) * 65 + kk + c];
      float4 b0 = *(const float4*)(wLDS + c * 128 + tx * 8);
      float4 b1 = *(const float4*)(wLDS + c * 128 + tx * 8 + 4);
      float b[8] = {b0.x, b0.y, b0.z, b0.w, b1.x, b1.y, b1.z, b1.w};
#pragma unroll
      for (int r = 0; r < 8; ++r)
#pragma unroll
        for (int j = 0; j < 8; ++j) acc[r][j] += a[r] * b[j];
    }
  }
  float4 bi0 = *(const float4*)(bias + tx * 8);
  float4 bi1 = *(const float4*)(bias + tx * 8 + 4);
#pragma unroll
  for (int r = 0; r < 8; ++r) {
    int grow = row0 + ty * 8 + r;
    if (grow < N) {
      float4 o0 = make_float4(acc[r][0] + bi0.x, acc[r][1] + bi0.y,
                              acc[r][2] + bi0.z, acc[r][3] + bi0.w);
      float4 o1 = make_float4(acc[r][4] + bi1.x, acc[r][5] + bi1.y,
                              acc[r][6] + bi1.z, acc[r][7] + bi1.w);
      float* dst = out + (size_t)grow * 128 + tx * 8;
      *(float4*)dst = o0;
      *(float4*)(dst + 4) = o1;
    }
  }
}

__global__ __launch_bounds__(256) void msg_gemm_buf(
    const float* __restrict__ f1, const float* __restrict__ f2,
    const float* __restrict__ W27, const int* __restrict__ G,
    const int* __restrict__ S, unsigned short* __restrict__ msgbuf,
    int N, int N1, int pm) {
  const int i = blockIdx.y;
  const int ktap = i + (i >= 13 ? 1 : 0);
  const float* W = W27 + (size_t)ktap * 64 * 128;
  const int* Gi = G + (size_t)i * pm;
  const int* Si = S + (size_t)i * pm;
  const int p0 = blockIdx.x * 128;
  if (Si[p0] >= N) return;
  __shared__ float fLDS[128 * 65];
  __shared__ float wLDS[32 * 128];
  const int tid = threadIdx.x;
  const int tx = tid & 15, ty = tid >> 4;
  for (int k = 0; k < 8; ++k) {
    int flat4 = tid + k * 256;
    int row = flat4 >> 4, c4 = flat4 & 15;
    int p = p0 + row;
    float4 v = make_float4(0.f, 0.f, 0.f, 0.f);
    if (p < pm) {
      int g = Gi[p];
      if (g < N) {
        const float* src = (g < N1) ? (f1 + (size_t)g * 64)
                                    : (f2 + (size_t)(g - N1) * 64);
        v = *(const float4*)(src + c4 * 4);
      }
    }
    int l = row * 65 + c4 * 4;
    fLDS[l + 0] = v.x; fLDS[l + 1] = v.y; fLDS[l + 2] = v.z; fLDS[l + 3] = v.w;
  }
  float acc[8][8];
#pragma unroll
  for (int r = 0; r < 8; ++r)
#pragma unroll
    for (int j = 0; j < 8; ++j) acc[r][j] = 0.f;
  for (int kk = 0; kk < 64; kk += 32) {
    __syncthreads();
    for (int k = 0; k < 4; ++k) {
      int flat4 = tid + k * 256;
      int c = flat4 >> 5, col4 = flat4 & 31;
      float4 v = *(const float4*)(W + (size_t)(kk + c) * 128 + col4 * 4);
      *(float4*)(wLDS + c * 128 + col4 * 4) = v;
    }
    __syncthreads();
#pragma unroll 4
    for (int c = 0; c < 32; ++c) {
      float a[8];
#pragma unroll
      for (int r = 0; r < 8; ++r) a[r] = fLDS[(ty * 8 + r) * 65 + kk + c];
      float4 b0 = *(const float4*)(wLDS + c * 128 + tx * 8);
      float4 b1 = *(const float4*)(wLDS + c * 128 + tx * 8 + 4);
      float b[8] = {b0.x, b0.y, b0.z, b0.w, b1.x, b1.y, b1.z, b1.w};
#pragma unroll
      for (int r = 0; r < 8; ++r)
#pragma unroll
        for (int j = 0; j < 8; ++j) acc[r][j] += a[r] * b[j];
    }
  }
#pragma unroll
  for (int r = 0; r < 8; ++r) {
    int p = p0 + ty * 8 + r;
    if (p < pm) {
      uint4 pk;
      pk.x = f2bf_pack(acc[r][0], acc[r][1]);
      pk.y = f2bf_pack(acc[r][2], acc[r][3]);
      pk.z = f2bf_pack(acc[r][4], acc[r][5]);
      pk.w = f2bf_pack(acc[r][6], acc[r][7]);
      *(uint4*)(msgbuf + ((size_t)i * pm + p) * 128 + tx * 8) = pk;
    }
  }
}

__global__ __launch_bounds__(256) void msg_gemm(
    const float* __restrict__ f1, const float* __restrict__ f2,
    const float* __restrict__ W27, const int* __restrict__ G,
    const int* __restrict__ S, float* __restrict__ out,
    int N, int N1, int pm) {
  const int i = blockIdx.y;
  const int ktap = i + (i >= 13 ? 1 : 0);
  const float* W = W27 + (size_t)ktap * 64 * 128;
  const int* Gi = G + (size_t)i * pm;
  const int* Si = S + (size_t)i * pm;
  const int p0 = blockIdx.x * 128;
  if (Si[p0] >= N) return;
  __shared__ float fLDS[128 * 65];
  __shared__ float wLDS[32 * 128];
  const int tid = threadIdx.x;
  const int tx = tid & 15, ty = tid >> 4;
  for (int k = 0; k < 8; ++k) {
    int flat4 = tid + k * 256;
    int row = flat4 >> 4, c4 = flat4 & 15;
    int p = p0 + row;
    float4 v = make_float4(0.f, 0.f, 0.f, 0.f);
    if (p < pm) {
      int g = Gi[p];
      if (g < N) {
        const float* src = (g < N1) ? (f1 + (size_t)g * 64)
                                    : (f2 + (size_t)(g - N1) * 64);
        v = *(const float4*)(src + c4 * 4);
      }
    }
    int l = row * 65 + c4 * 4;
    fLDS[l + 0] = v.x; fLDS[l + 1] = v.y; fLDS[l + 2] = v.z; fLDS[l + 3] = v.w;
  }
  float acc[8][8];
#pragma unroll
  for (int r = 0; r < 8; ++r)
#pragma unroll
    for (int j = 0; j < 8; ++j) acc[r][j] = 0.f;
  for (int kk = 0; kk < 64; kk += 32) {
    __syncthreads();
    for (int k = 0; k < 4; ++k) {
      int flat4 = tid + k * 256;
      int c = flat4 >> 5, col4 = flat4 & 31;
      float4 v = *(const float4*)(W + (size_t)(kk + c) * 128 + col4 * 4);
      *(float4*)(wLDS + c * 128 + col4 * 4) = v;
    }
    __syncthreads();
#pragma unroll 4
    for (int c = 0; c < 32; ++c) {
      float a[8];
#pragma unroll
      for (int r = 0; r < 8; ++r) a[r] = fLDS[(ty * 8 + r) * 65 + kk + c];
      float4 b0 = *(const float4*)(wLDS + c * 128 + tx * 8);
      float4 b1 = *(const float4*)(wLDS + c * 128 + tx * 8 + 4);
      float b[8] = {b0.x, b0.y, b0.z, b0.w, b1.x, b1.y, b1.z, b1.w};
#pragma unroll
      for (int r = 0; r < 8; ++r)
#pragma unroll
        for (int j = 0; j < 8; ++j) acc[r][j] += a[r] * b[j];
    }
  }
#pragma unroll
  for (int r = 0; r < 8; ++r) {
    int p = p0 + ty * 8 + r;
    if (p < pm) {
      int s = Si[p];
      if (s < N) {
        float* dst = out + (size_t)s * 128 + tx * 8;
#pragma unroll
        for (int j = 0; j < 8; ++j) unsafeAtomicAdd(dst + j, acc[r][j]);
      }
    }
  }
}

__global__ __launch_bounds__(256) void combine_stats(
    float* __restrict__ out, const int* __restrict__ R,
    const unsigned short* __restrict__ msgbuf, float* __restrict__ ws,
    int N) {
  const int tid = threadIdx.x;
  const int grp = tid >> 5, l = tid & 31;
  const int base = tid & 32;
  float4 s = make_float4(0.f, 0.f, 0.f, 0.f);
  float4 q = make_float4(0.f, 0.f, 0.f, 0.f);
  for (int j = blockIdx.x * 8 + grp; j < N; j += gridDim.x * 8) {
    float4 v = ((const float4*)(out + (size_t)j * 128))[l];
    int r = (l < 26) ? R[(size_t)j * 26 + l] : -1;
    unsigned long long bal = __ballot(r >= 0);
    unsigned mym = (unsigned)((bal >> base) & 0x3FFFFFFull);
    const bool any = (mym != 0);
    while (mym) {
      int b = __builtin_ctz(mym);
      mym &= mym - 1;
      int ptr = __shfl(r, base + b, 64);
      uint2 mv = ((const uint2*)(msgbuf + (size_t)ptr * 128))[l];
      v.x += bf2f(mv.x & 0xffffu);
      v.y += bf2f(mv.x >> 16);
      v.z += bf2f(mv.y & 0xffffu);
      v.w += bf2f(mv.y >> 16);
    }
    if (any) ((float4*)(out + (size_t)j * 128))[l] = v;
    s.x += v.x; s.y += v.y; s.z += v.z; s.w += v.w;
    q.x += v.x * v.x; q.y += v.y * v.y; q.z += v.z * v.z; q.w += v.w * v.w;
  }
  __shared__ float red[8 * 32 * 8];
  float* my = red + (grp * 32 + l) * 8;
  my[0] = s.x; my[1] = s.y; my[2] = s.z; my[3] = s.w;
  my[4] = q.x; my[5] = q.y; my[6] = q.z; my[7] = q.w;
  __syncthreads();
  {
    int c4 = tid & 31, j = tid >> 5;
    float v = 0.f;
#pragma unroll
    for (int g = 0; g < 8; ++g) v += red[(g * 32 + c4) * 8 + j];
    int col = c4 * 4 + (j & 3);
    unsafeAtomicAdd(&ws[col + (j >> 2) * 128], v);
  }
}

__global__ __launch_bounds__(256) void stats_kernel(
    const float* __restrict__ out, float* __restrict__ ws, int total4) {
  const int tid = threadIdx.x;
  float4 s = make_float4(0.f, 0.f, 0.f, 0.f);
  float4 q = make_float4(0.f, 0.f, 0.f, 0.f);
  const float4* o4 = (const float4*)out;
  for (int idx = blockIdx.x * 256 + tid; idx < total4; idx += gridDim.x * 256) {
    float4 v = o4[idx];
    s.x += v.x; s.y += v.y; s.z += v.z; s.w += v.w;
    q.x += v.x * v.x; q.y += v.y * v.y; q.z += v.z * v.z; q.w += v.w * v.w;
  }
  __shared__ float red[8 * 32 * 8];
  const int col4 = tid & 31, grpq = tid >> 5;
  float* my = red + (grpq * 32 + col4) * 8;
  my[0] = s.x; my[1] = s.y; my[2] = s.z; my[3] = s.w;
  my[4] = q.x; my[5] = q.y; my[6] = q.z; my[7] = q.w;
  __syncthreads();
  {
    int c4 = tid & 31, j = tid >> 5;
    float v = 0.f;
#pragma unroll
    for (int g = 0; g < 8; ++g) v += red[(g * 32 + c4) * 8 + j];
    int col = c4 * 4 + (j & 3);
    unsafeAtomicAdd(&ws[col + (j >> 2) * 128], v);
  }
}

__global__ __launch_bounds__(256) void norm_kernel(
    float* __restrict__ out, const float* __restrict__ ws,
    const float* __restrict__ gamma, const float* __restrict__ beta,
    int total4, float invN) {
  const int tid = threadIdx.x;
  const int c4 = tid & 31;
  float4 s = ((const float4*)ws)[c4];
  float4 q = ((const float4*)ws)[32 + c4];
  float4 g = ((const float4*)gamma)[c4];
  float4 b = ((const float4*)beta)[c4];
  float m0 = s.x * invN, m1 = s.y * invN, m2 = s.z * invN, m3 = s.w * invN;
  float sc0 = g.x * rsqrtf(q.x * invN - m0 * m0 + EPS);
  float sc1 = g.y * rsqrtf(q.y * invN - m1 * m1 + EPS);
  float sc2 = g.z * rsqrtf(q.z * invN - m2 * m2 + EPS);
  float sc3 = g.w * rsqrtf(q.w * invN - m3 * m3 + EPS);
  float sh0 = b.x - m0 * sc0, sh1 = b.y - m1 * sc1;
  float sh2 = b.z - m2 * sc2, sh3 = b.w - m3 * sc3;
  float4* o4 = (float4*)out;
  for (int idx = blockIdx.x * 256 + tid; idx < total4; idx += gridDim.x * 256) {
    float4 v = o4[idx];
    v.x = fmaxf(v.x * sc0 + sh0, 0.f);
    v.y = fmaxf(v.y * sc1 + sh1, 0.f);
    v.z = fmaxf(v.z * sc2 + sh2, 0.f);
    v.w = fmaxf(v.w * sc3 + sh3, 0.f);
    o4[idx] = v;
  }
}

// ===========================================================================
extern "C" void kernel_launch(void* const* d_in, const int* in_sizes, int n_in,
                              void* d_out, int out_size, void* d_ws, size_t ws_size,
                              hipStream_t stream) {
  const float* f1 = (const float*)d_in[0];
  const float* f2 = (const float*)d_in[1];
  const float* W = (const float*)d_in[2];
  const float* bias = (const float*)d_in[3];
  const float* gamma = (const float*)d_in[4];
  const float* beta = (const float*)d_in[5];
  const int* G = (const int*)d_in[6];
  const int* S = (const int*)d_in[7];
  const int N1 = in_sizes[0] / 64;
  const int N2 = in_sizes[1] / 64;
  const int N = N1 + N2;
  const int pm = in_sizes[6] / 26;
  float* out = (float*)d_out;
  float* ws = (float*)d_ws;

  const size_t AL = 255;
  // full path layout (padded stats + gtot in first 32 KB; cnt right after
  // so one memset covers both)
  const size_t offC = 32768;                       // cnt: N ints
  const size_t Cb = (size_t)N * 4;
  const size_t offBC = (offC + Cb + AL) & ~AL;     // BC: N int2
  const size_t BCb = (size_t)N * 8;
  const size_t offSL = (offBC + BCb + AL) & ~AL;   // SL: 26*pm bytes
  const size_t SLb = (size_t)26 * pm;
  const size_t offF = (offSL + SLb + AL) & ~AL;    // fbuf: (N+1) x 64 bf16
  const size_t Fb = (size_t)(N + 1) * 64 * 2;
  const size_t offW = (offF + Fb + AL) & ~AL;
  const size_t Wbyt = (size_t)27 * 128 * 64 * 2;
  const size_t offM = (offW + Wbyt + AL) & ~AL;
  const size_t Mb = (size_t)26 * pm * 128 * 2;     // compact (messages only)
  const size_t offO = (offM + Mb + AL) & ~AL;
  const size_t Ob = (size_t)N * 128 * 2;
  const bool full = ws_size >= offO + Ob;

  // fp32 fallback layout (unpadded stats: 1 KB)
  const size_t Rb = (size_t)N * 26 * 4;
  const size_t offR2 = 1024;
  const size_t offM2 = (offR2 + Rb + AL) & ~AL;
  const bool fast2 = ws_size >= offM2 + Mb;

  if (full) {
    int* cnt = (int*)((char*)d_ws + offC);
    int2* BC = (int2*)((char*)d_ws + offBC);
    unsigned char* SLp = (unsigned char*)((char*)d_ws + offSL);
    unsigned short* fbuf = (unsigned short*)((char*)d_ws + offF);
    unsigned short* Wb = (unsigned short*)((char*)d_ws + offW);
    unsigned short* compact = (unsigned short*)((char*)d_ws + offM);
    unsigned short* outb = (unsigned short*)((char*)d_ws + offO);
    int* gtot = (int*)((char*)d_ws + 28672);  // inside zeroed stats block

    const int wblocks = (27 * 128 * 64) / 256;     // 864
    const int fblocks = ((N + 1) * 8 + 255) / 256;
    const int cpb256 = (pm + 255) / 256;
    const int cpb128 = (pm + 127) / 128;
    const int cblocks = (N + 127) / 128;

    (void)hipMemsetAsync(ws, 0, offC + Cb, stream);  // stats + gtot + cnt
    prep<<<wblocks + fblocks + 26 * cpb256, 256, 0, stream>>>(
        W, Wb, f1, f2, fbuf, S, SLp, cnt, N, N1, pm, wblocks, fblocks,
        cpb256);
    prefix_base<<<(N + 1023) / 1024, 256, 0, stream>>>(cnt, BC, gtot, N);
    msg_mfma_c<<<dim3(cpb128, 26), 256, 0, stream>>>(
        fbuf, Wb, G, S, BC, SLp, compact, N, pm);
    center_combine<<<cblocks, 256, 0, stream>>>(
        fbuf, Wb + (size_t)13 * 128 * 64, bias, BC, compact, outb, ws, N);
    norm_b<<<2048, 256, 0, stream>>>(outb, out, ws, gamma, beta, N * 16,
                                     1.0f / N);
  } else if (fast2) {
    int* R = (int*)((char*)d_ws + offR2);
    unsigned short* msgbuf = (unsigned short*)((char*)d_ws + offM2);
    (void)hipMemsetAsync(ws, 0, 256 * sizeof(float), stream);
    (void)hipMemsetAsync(R, 0xFF, Rb, stream);
    center_gemm<<<(N + 127) / 128, 256, 0, stream>>>(
        f1, f2, W + (size_t)13 * 64 * 128, bias, out, N, N1);
    scatter_R<<<dim3((pm + 255) / 256, 26), 256, 0, stream>>>(S, R, N, pm);
    msg_gemm_buf<<<dim3((pm + 127) / 128, 26), 256, 0, stream>>>(
        f1, f2, W, G, S, msgbuf, N, N1, pm);
    combine_stats<<<1024, 256, 0, stream>>>(out, R, msgbuf, ws, N);
    norm_kernel<<<2048, 256, 0, stream>>>(out, ws, gamma, beta, N * 32,
                                          1.0f / N);
  } else {
    (void)hipMemsetAsync(ws, 0, 256 * sizeof(float), stream);
    center_gemm<<<(N + 127) / 128, 256, 0, stream>>>(
        f1, f2, W + (size_t)13 * 64 * 128, bias, out, N, N1);
    msg_gemm<<<dim3((pm + 127) / 128, 26), 256, 0, stream>>>(
        f1, f2, W, G, S, out, N, N1, pm);
    stats_kernel<<<1024, 256, 0, stream>>>(out, ws, N * 32);
    norm_kernel<<<2048, 256, 0, stream>>>(out, ws, gamma, beta, N * 32,
                                          1.0f / N);
  }
}

// Round 11
// 291.772 us; speedup vs baseline: 1.1104x; 1.1099x over previous
//
#include <hip/hip_runtime.h>

#define EPS 1e-3f

typedef __attribute__((ext_vector_type(8))) short bf8_t;   // 8 bf16 (4 VGPRs)
typedef __attribute__((ext_vector_type(4))) float f32x4;   // MFMA acc

static __device__ __forceinline__ unsigned f2bf_pack(float a, float b) {
  union { float f; unsigned u; } ca, cb;
  ca.f = a; cb.f = b;
  unsigned ra = (ca.u + 0x7FFFu + ((ca.u >> 16) & 1u)) >> 16;
  unsigned rb = (cb.u + 0x7FFFu + ((cb.u >> 16) & 1u)) >> 16;
  return ra | (rb << 16);
}
static __device__ __forceinline__ unsigned short f2bf1(float x) {
  union { float f; unsigned u; } c; c.f = x;
  return (unsigned short)((c.u + 0x7FFFu + ((c.u >> 16) & 1u)) >> 16);
}
static __device__ __forceinline__ float bf2f(unsigned bits16) {
  union { unsigned u; float f; } c;
  c.u = bits16 << 16;
  return c.f;
}

// ===========================================================================
// FULL (MFMA + bf16) PATH — destination-compacted messages (msgs only),
// center fused with combine+stats (128-row tile, stride-132 rowbuf,
// 16-lane-group combine, unroll-4 message MLP).
// ws layout: [0,32KB) padded stats (sum[c] @ c*16 floats, sumsq @ 4096+c*16,
//            gtot @ byte 28672) | cnt (@32KB, one memset covers both) | BC |
//            SL | fbuf | Wb | compact | outb
// Dispatches: memset | prep | prefix | msg | center_combine | norm  (6)
// ===========================================================================

// fused: Wb transpose-convert | feats fp32->bf16 fbuf | per-(tap,p) slot grab
__global__ __launch_bounds__(256) void prep(
    const float* __restrict__ W, unsigned short* __restrict__ Wb,
    const float* __restrict__ f1, const float* __restrict__ f2,
    unsigned short* __restrict__ fbuf,
    const int* __restrict__ S, unsigned char* __restrict__ SL,
    int* __restrict__ cnt, int N, int N1, int pm,
    int wblocks, int fblocks, int cpb) {
  const int bid = blockIdx.x;
  if (bid < wblocks) {
    // W[27][64][128] fp32 -> Wb[27][128][64] bf16 (27*128*64 = 864 blocks)
    int idx = bid * 256 + threadIdx.x;
    int k = idx & 63, n = (idx >> 6) & 127, t = idx >> 13;
    Wb[idx] = f2bf1(W[((size_t)t * 64 + k) * 128 + n]);
  } else if (bid < wblocks + fblocks) {
    // feats (f1|f2) fp32 -> fbuf bf16, (N+1) rows x 64, row N = zeros
    int idx = (bid - wblocks) * 256 + threadIdx.x;  // (N+1)*8 segs of 8
    if (idx >= (N + 1) * 8) return;
    int row = idx >> 3, seg = idx & 7;
    uint4 o = make_uint4(0, 0, 0, 0);
    if (row < N) {
      const float* src = (row < N1) ? (f1 + (size_t)row * 64)
                                    : (f2 + (size_t)(row - N1) * 64);
      float4 v0 = *(const float4*)(src + seg * 8);
      float4 v1 = *(const float4*)(src + seg * 8 + 4);
      o.x = f2bf_pack(v0.x, v0.y); o.y = f2bf_pack(v0.z, v0.w);
      o.z = f2bf_pack(v1.x, v1.y); o.w = f2bf_pack(v1.z, v1.w);
    }
    *(uint4*)(fbuf + (size_t)idx * 8) = o;
  } else {
    int b = bid - wblocks - fblocks;
    int tap = b / cpb;
    int p = (b - tap * cpb) * 256 + threadIdx.x;
    if (p >= pm) return;
    const int idx = tap * pm + p;
    const int s = S[idx];
    if (s < N) SL[idx] = (unsigned char)atomicAdd(&cnt[s], 1);  // max 26/row
  }
}

// exclusive prefix over cnt -> BC[j] = (base, cnt). Block order arbitrary
// (atomic chunk base) but stored, hence consistent for all consumers.
__global__ __launch_bounds__(256) void prefix_base(
    const int* __restrict__ cnt, int2* __restrict__ BC,
    int* __restrict__ gtot, int N) {
  const int t = threadIdx.x;
  const int j0 = blockIdx.x * 1024 + t * 4;
  int c0 = 0, c1 = 0, c2 = 0, c3 = 0;
  if (j0 + 3 < N) {
    int4 c = *(const int4*)(cnt + j0);
    c0 = c.x; c1 = c.y; c2 = c.z; c3 = c.w;
  } else {
    if (j0 < N) c0 = cnt[j0];
    if (j0 + 1 < N) c1 = cnt[j0 + 1];
    if (j0 + 2 < N) c2 = cnt[j0 + 2];
  }
  const int tsum = c0 + c1 + c2 + c3;
  int incl = tsum;
#pragma unroll
  for (int off = 1; off < 64; off <<= 1) {
    int u = __shfl_up(incl, off, 64);
    if ((t & 63) >= off) incl += u;
  }
  __shared__ int wsum[4];
  if ((t & 63) == 63) wsum[t >> 6] = incl;
  __syncthreads();
  if (t == 0) {
    int w0 = wsum[0], w1 = wsum[1], w2 = wsum[2], w3 = wsum[3];
    int gb = atomicAdd(gtot, w0 + w1 + w2 + w3);
    wsum[0] = gb; wsum[1] = gb + w0;
    wsum[2] = gb + w0 + w1; wsum[3] = gb + w0 + w1 + w2;
  }
  __syncthreads();
  const int excl = wsum[t >> 6] + incl - tsum;
  if (j0 < N) BC[j0] = make_int2(excl, c0);
  if (j0 + 1 < N) BC[j0 + 1] = make_int2(excl + c0, c1);
  if (j0 + 2 < N) BC[j0 + 2] = make_int2(excl + c0 + c1, c2);
  if (j0 + 3 < N) BC[j0 + 3] = make_int2(excl + c0 + c1 + c2, c3);
}

// 26 neighbor taps -> compact[(BC[s].x + SL[tap,p])*128 + col]
__global__ __launch_bounds__(256) void msg_mfma_c(
    const unsigned short* __restrict__ fbuf,
    const unsigned short* __restrict__ Wb,
    const int* __restrict__ G, const int* __restrict__ S,
    const int2* __restrict__ BC, const unsigned char* __restrict__ SL,
    unsigned short* __restrict__ compact, int N, int pm) {
  const int tap = blockIdx.y;                 // tap index (0..25)
  const int ktap = tap + (tap >= 13 ? 1 : 0);
  const unsigned short* Wt = Wb + (size_t)ktap * 128 * 64;
  const int* Gi = G + (size_t)tap * pm;
  const int* Si = S + (size_t)tap * pm;
  const int p0 = blockIdx.x * 128;
  if (Gi[p0] >= N) return;  // fully-padded tail block (padding G == N)

  __shared__ unsigned short A[128 * 64];
  __shared__ int g_lds[128];
  __shared__ int d_lds[128];
  const int tid = threadIdx.x;
  if (tid < 128) {
    int p = p0 + tid;
    int g = N, d = -1;
    if (p < pm) {
      g = Gi[p];
      int s = Si[p];
      if (s < N) d = BC[s].x + (int)SL[(size_t)tap * pm + p];
    }
    g_lds[tid] = g;
    d_lds[tid] = d;
  }
  __syncthreads();

#pragma unroll
  for (int it = 0; it < 4; ++it) {
    int flat = it * 256 + tid;       // 128 rows x 8 segs of 8 bf16
    int r = flat >> 3, qs = flat & 7;
    int g = g_lds[r];                 // g in [0,N]; row N is zeros
    uint4 v = *(const uint4*)(fbuf + (size_t)g * 64 + qs * 8);
    int rt = r >> 4, m = r & 15, c = qs >> 2, qq = qs & 3;
    *(uint4*)(A + ((rt * 2 + c) * 64 + qq * 16 + m) * 8) = v;
  }
  __syncthreads();

  const int wave = tid >> 6, lane = tid & 63;
  const int ncol = lane & 15, q2 = lane >> 4;
  bf8_t Bf[2][2];
#pragma unroll
  for (int ct = 0; ct < 2; ++ct) {
    int col = wave * 32 + ct * 16 + ncol;
#pragma unroll
    for (int c = 0; c < 2; ++c)
      Bf[ct][c] = *(const bf8_t*)(Wt + (size_t)col * 64 + c * 32 + q2 * 8);
  }
  f32x4 acc[8][2];
#pragma unroll
  for (int rt = 0; rt < 8; ++rt)
#pragma unroll
    for (int ct = 0; ct < 2; ++ct) acc[rt][ct] = (f32x4){0.f, 0.f, 0.f, 0.f};

#pragma unroll
  for (int rt = 0; rt < 8; ++rt) {
    bf8_t a0 = *(const bf8_t*)(A + ((rt * 2 + 0) * 64 + lane) * 8);
    bf8_t a1 = *(const bf8_t*)(A + ((rt * 2 + 1) * 64 + lane) * 8);
#pragma unroll
    for (int ct = 0; ct < 2; ++ct) {
      acc[rt][ct] = __builtin_amdgcn_mfma_f32_16x16x32_bf16(a0, Bf[ct][0], acc[rt][ct], 0, 0, 0);
      acc[rt][ct] = __builtin_amdgcn_mfma_f32_16x16x32_bf16(a1, Bf[ct][1], acc[rt][ct], 0, 0, 0);
    }
  }

#pragma unroll
  for (int rt = 0; rt < 8; ++rt) {
    int dl[4];
#pragma unroll
    for (int e = 0; e < 4; ++e) dl[e] = d_lds[rt * 16 + q2 * 4 + e];
#pragma unroll
    for (int ct = 0; ct < 2; ++ct) {
      int col = wave * 32 + ct * 16 + ncol;
#pragma unroll
      for (int e = 0; e < 4; ++e)
        if (dl[e] >= 0)
          compact[(size_t)dl[e] * 128 + col] = f2bf1(acc[rt][ct][e]);
    }
  }
}

// center MFMA + coalesced message combine + stats, one kernel (128-row tile).
// Phase 1: stage 128 center rows (bf16) into SH[:16K], MFMA (8 rt).
// Phase 2: park bf16(center+bias) in SH rowbuf[128][132] (264 B/row ->
//          q2-rows hit banks +0/8/16/24, conflict-free park).
// Phase 3: 16 x 16-lane groups, 8 rows each (unroll 4 for deep MLP):
//          center from LDS + contiguous compact rows (uint4/lane) ->
//          outb + stats.
__global__ __launch_bounds__(256) void center_combine(
    const unsigned short* __restrict__ fbuf,
    const unsigned short* __restrict__ Wb13, const float* __restrict__ bias,
    const int2* __restrict__ BC, const unsigned short* __restrict__ compact,
    unsigned short* __restrict__ outb, float* __restrict__ ws, int N) {
  __shared__ unsigned short SH[128 * 132];  // 33 KB; [:16K) doubles as A
  __shared__ int2 bc_lds[128];
  const int tid = threadIdx.x;
  const int row0 = blockIdx.x * 128;

  if (tid < 128) {
    int j = row0 + tid;
    bc_lds[tid] = (j < N) ? BC[j] : make_int2(0, 0);
  }

  // ---- stage A (center rows, sequential fbuf reads): 128 rows x 8 segs ----
#pragma unroll
  for (int it = 0; it < 4; ++it) {
    int flat = it * 256 + tid;
    int r = flat >> 3, qs = flat & 7;
    int g = row0 + r; if (g >= N) g = N;  // row N is zeros
    uint4 v = *(const uint4*)(fbuf + (size_t)g * 64 + qs * 8);
    int rt = r >> 4, m = r & 15, c = qs >> 2, qq = qs & 3;
    *(uint4*)(SH + ((rt * 2 + c) * 64 + qq * 16 + m) * 8) = v;
  }
  __syncthreads();

  const int wave = tid >> 6, lane = tid & 63;
  const int ncol = lane & 15, q2 = lane >> 4;
  bf8_t Bf[2][2];
  float bs[2];
#pragma unroll
  for (int ct = 0; ct < 2; ++ct) {
    int col = wave * 32 + ct * 16 + ncol;
    bs[ct] = bias[col];
#pragma unroll
    for (int c = 0; c < 2; ++c)
      Bf[ct][c] = *(const bf8_t*)(Wb13 + (size_t)col * 64 + c * 32 + q2 * 8);
  }
  f32x4 acc[8][2];
#pragma unroll
  for (int rt = 0; rt < 8; ++rt)
#pragma unroll
    for (int ct = 0; ct < 2; ++ct) acc[rt][ct] = (f32x4){0.f, 0.f, 0.f, 0.f};

#pragma unroll
  for (int rt = 0; rt < 8; ++rt) {
    bf8_t a0 = *(const bf8_t*)(SH + ((rt * 2 + 0) * 64 + lane) * 8);
    bf8_t a1 = *(const bf8_t*)(SH + ((rt * 2 + 1) * 64 + lane) * 8);
#pragma unroll
    for (int ct = 0; ct < 2; ++ct) {
      acc[rt][ct] = __builtin_amdgcn_mfma_f32_16x16x32_bf16(a0, Bf[ct][0], acc[rt][ct], 0, 0, 0);
      acc[rt][ct] = __builtin_amdgcn_mfma_f32_16x16x32_bf16(a1, Bf[ct][1], acc[rt][ct], 0, 0, 0);
    }
  }
  __syncthreads();  // all A reads done; SH becomes rowbuf (stride 132)

  // ---- park bf16(center+bias) into rowbuf SH[row][col], stride 132 ----
#pragma unroll
  for (int rt = 0; rt < 8; ++rt)
#pragma unroll
    for (int ct = 0; ct < 2; ++ct) {
      int col = wave * 32 + ct * 16 + ncol;
#pragma unroll
      for (int e = 0; e < 4; ++e)
        SH[(rt * 16 + q2 * 4 + e) * 132 + col] = f2bf1(acc[rt][ct][e] + bs[ct]);
    }
  __syncthreads();

  // ---- coalesced combine: 16 groups x 8 rows, uint4 (16 B) per lane ----
  const int grp = tid >> 4, l = tid & 15;
  float s[8], q[8];
#pragma unroll
  for (int c = 0; c < 8; ++c) { s[c] = 0.f; q[c] = 0.f; }
#pragma unroll 4
  for (int i = 0; i < 8; ++i) {
    int r = grp * 8 + i;
    int j = row0 + r;
    if (j < N) {
      int2 bc = bc_lds[r];  // uniform across group -> broadcast
      uint4 cv = *(const uint4*)(SH + r * 132 + l * 8);
      float v[8];
      v[0] = bf2f(cv.x & 0xffffu); v[1] = bf2f(cv.x >> 16);
      v[2] = bf2f(cv.y & 0xffffu); v[3] = bf2f(cv.y >> 16);
      v[4] = bf2f(cv.z & 0xffffu); v[5] = bf2f(cv.z >> 16);
      v[6] = bf2f(cv.w & 0xffffu); v[7] = bf2f(cv.w >> 16);
      for (int k = 0; k < bc.y; ++k) {
        uint4 mv = ((const uint4*)(compact + (size_t)(bc.x + k) * 128))[l];
        v[0] += bf2f(mv.x & 0xffffu); v[1] += bf2f(mv.x >> 16);
        v[2] += bf2f(mv.y & 0xffffu); v[3] += bf2f(mv.y >> 16);
        v[4] += bf2f(mv.z & 0xffffu); v[5] += bf2f(mv.z >> 16);
        v[6] += bf2f(mv.w & 0xffffu); v[7] += bf2f(mv.w >> 16);
      }
      uint4 pk;
      pk.x = f2bf_pack(v[0], v[1]); pk.y = f2bf_pack(v[2], v[3]);
      pk.z = f2bf_pack(v[4], v[5]); pk.w = f2bf_pack(v[6], v[7]);
      ((uint4*)(outb + (size_t)j * 128))[l] = pk;
#pragma unroll
      for (int c = 0; c < 8; ++c) { s[c] += v[c]; q[c] += v[c] * v[c]; }
    }
  }

  // ---- stats reduce (reuse SH as float scratch; 256 recs x 17 = 17 KB) ----
  __syncthreads();
  float* red = (float*)SH;
  float* my = red + (grp * 16 + l) * 17;
#pragma unroll
  for (int c = 0; c < 8; ++c) { my[c] = s[c]; my[8 + c] = q[c]; }
  __syncthreads();
  {
    int c = tid & 127, stat = tid >> 7;       // stat 0=sum, 1=sumsq
    int lane16 = c >> 3, idx = (c & 7) + (stat ? 8 : 0);
    float v = 0.f;
#pragma unroll
    for (int g = 0; g < 16; ++g) v += red[(g * 16 + lane16) * 17 + idx];
    // sum[col] @ ws[col*16]; sumsq[col] @ ws[4096 + col*16]  (64B apart)
    unsafeAtomicAdd(&ws[stat * 4096 + c * 16], v);
  }
}

// normalize bf16 pre-norm buffer -> fp32 final out (reads padded stats)
__global__ __launch_bounds__(256) void norm_b(
    const unsigned short* __restrict__ outb, float* __restrict__ out,
    const float* __restrict__ ws, const float* __restrict__ gamma,
    const float* __restrict__ beta, int total8, float invN) {
  const int tid0 = blockIdx.x * 256 + threadIdx.x;
  const int c0 = (tid0 & 15) * 8;
  float sc[8], sh[8];
#pragma unroll
  for (int k = 0; k < 8; ++k) {
    float m = ws[(c0 + k) * 16] * invN;
    float var = ws[4096 + (c0 + k) * 16] * invN - m * m;
    sc[k] = gamma[c0 + k] * rsqrtf(var + EPS);
    sh[k] = beta[c0 + k] - m * sc[k];
  }
  for (int idx = tid0; idx < total8; idx += gridDim.x * 256) {
    uint4 v = *(const uint4*)(outb + (size_t)idx * 8);
    float f0 = bf2f(v.x & 0xffffu), f1 = bf2f(v.x >> 16);
    float f2 = bf2f(v.y & 0xffffu), f3 = bf2f(v.y >> 16);
    float f4 = bf2f(v.z & 0xffffu), f5 = bf2f(v.z >> 16);
    float f6 = bf2f(v.w & 0xffffu), f7 = bf2f(v.w >> 16);
    float4 o0, o1;
    o0.x = fmaxf(f0 * sc[0] + sh[0], 0.f);
    o0.y = fmaxf(f1 * sc[1] + sh[1], 0.f);
    o0.z = fmaxf(f2 * sc[2] + sh[2], 0.f);
    o0.w = fmaxf(f3 * sc[3] + sh[3], 0.f);
    o1.x = fmaxf(f4 * sc[4] + sh[4], 0.f);
    o1.y = fmaxf(f5 * sc[5] + sh[5], 0.f);
    o1.z = fmaxf(f6 * sc[6] + sh[6], 0.f);
    o1.w = fmaxf(f7 * sc[7] + sh[7], 0.f);
    *(float4*)(out + (size_t)idx * 8) = o0;
    *(float4*)(out + (size_t)idx * 8 + 4) = o1;
  }
}

// ===========================================================================
// FALLBACK PATHS (fp32 pipelines for small workspace)
// (unpadded ws stats layout: sum @ ws[0..128), sumsq @ ws[128..256))
// ===========================================================================

__global__ __launch_bounds__(256) void scatter_R(
    const int* __restrict__ S, int* __restrict__ R, int N, int pm) {
  const int p = blockIdx.x * 256 + threadIdx.x;
  const int i = blockIdx.y;
  if (p >= pm) return;
  const int idx = i * pm + p;
  const int s = S[idx];
  if (s < N) R[(size_t)s * 26 + i] = idx;
}

__global__ __launch_bounds__(256) void center_gemm(
    const float* __restrict__ f1, const float* __restrict__ f2,
    const float* __restrict__ W, const float* __restrict__ bias,
    float* __restrict__ out, int N, int N1) {
  __shared__ float fLDS[128 * 65];
  __shared__ float wLDS[32 * 128];
  const int tid = threadIdx.x;
  const int tx = tid & 15, ty = tid >> 4;
  const int row0 = blockIdx.x * 128;

  for (int k = 0; k < 8; ++k) {
    int flat4 = tid + k * 256;
    int row = flat4 >> 4, c4 = flat4 & 15;
    int grow = row0 + row;
    float4 v = make_float4(0.f, 0.f, 0.f, 0.f);
    if (grow < N) {
      const float* src = (grow < N1) ? (f1 + (size_t)grow * 64)
                                     : (f2 + (size_t)(grow - N1) * 64);
      v = *(const float4*)(src + c4 * 4);
    }
    int l = row * 65 + c4 * 4;
    fLDS[l + 0] = v.x; fLDS[l + 1] = v.y; fLDS[l + 2] = v.z; fLDS[l + 3] = v.w;
  }
  float acc[8][8];
#pragma unroll
  for (int r = 0; r < 8; ++r)
#pragma unroll
    for (int j = 0; j < 8; ++j) acc[r][j] = 0.f;
  for (int kk = 0; kk < 64; kk += 32) {
    __syncthreads();
    for (int k = 0; k < 4; ++k) {
      int flat4 = tid + k * 256;
      int c = flat4 >> 5, col4 = flat4 & 31;
      float4 v = *(const float4*)(W + (size_t)(kk + c) * 128 + col4 * 4);
      *(float4*)(wLDS + c * 128 + col4 * 4) = v;
    }
    __syncthreads();
#pragma unroll 4
    for (int c = 0; c < 32; ++c) {
      float a[8];
#pragma unroll
      for (int r = 0; r < 8; ++r) a[r] = fLDS[(ty * 8 + r) * 65 + kk + c];
      float4 b0 = *(const float4*)(wLDS + c * 128 + tx * 8);
      float4 b1 = *(const float4*)(wLDS + c * 128 + tx * 8 + 4);
      float b[8] = {b0.x, b0.y, b0.z, b0.w, b1.x, b1.y, b1.z, b1.w};
#pragma unroll
      for (int r = 0; r < 8; ++r)
#pragma unroll
        for (int j = 0; j < 8; ++j) acc[r][j] += a[r] * b[j];
    }
  }
  float4 bi0 = *(const float4*)(bias + tx * 8);
  float4 bi1 = *(const float4*)(bias + tx * 8 + 4);
#pragma unroll
  for (int r = 0; r < 8; ++r) {
    int grow = row0 + ty * 8 + r;
    if (grow < N) {
      float4 o0 = make_float4(acc[r][0] + bi0.x, acc[r][1] + bi0.y,
                              acc[r][2] + bi0.z, acc[r][3] + bi0.w);
      float4 o1 = make_float4(acc[r][4] + bi1.x, acc[r][5] + bi1.y,
                              acc[r][6] + bi1.z, acc[r][7] + bi1.w);
      float* dst = out + (size_t)grow * 128 + tx * 8;
      *(float4*)dst = o0;
      *(float4*)(dst + 4) = o1;
    }
  }
}

__global__ __launch_bounds__(256) void msg_gemm_buf(
    const float* __restrict__ f1, const float* __restrict__ f2,
    const float* __restrict__ W27, const int* __restrict__ G,
    const int* __restrict__ S, unsigned short* __restrict__ msgbuf,
    int N, int N1, int pm) {
  const int i = blockIdx.y;
  const int ktap = i + (i >= 13 ? 1 : 0);
  const float* W = W27 + (size_t)ktap * 64 * 128;
  const int* Gi = G + (size_t)i * pm;
  const int* Si = S + (size_t)i * pm;
  const int p0 = blockIdx.x * 128;
  if (Si[p0] >= N) return;
  __shared__ float fLDS[128 * 65];
  __shared__ float wLDS[32 * 128];
  const int tid = threadIdx.x;
  const int tx = tid & 15, ty = tid >> 4;
  for (int k = 0; k < 8; ++k) {
    int flat4 = tid + k * 256;
    int row = flat4 >> 4, c4 = flat4 & 15;
    int p = p0 + row;
    float4 v = make_float4(0.f, 0.f, 0.f, 0.f);
    if (p < pm) {
      int g = Gi[p];
      if (g < N) {
        const float* src = (g < N1) ? (f1 + (size_t)g * 64)
                                    : (f2 + (size_t)(g - N1) * 64);
        v = *(const float4*)(src + c4 * 4);
      }
    }
    int l = row * 65 + c4 * 4;
    fLDS[l + 0] = v.x; fLDS[l + 1] = v.y; fLDS[l + 2] = v.z; fLDS[l + 3] = v.w;
  }
  float acc[8][8];
#pragma unroll
  for (int r = 0; r < 8; ++r)
#pragma unroll
    for (int j = 0; j < 8; ++j) acc[r][j] = 0.f;
  for (int kk = 0; kk < 64; kk += 32) {
    __syncthreads();
    for (int k = 0; k < 4; ++k) {
      int flat4 = tid + k * 256;
      int c = flat4 >> 5, col4 = flat4 & 31;
      float4 v = *(const float4*)(W + (size_t)(kk + c) * 128 + col4 * 4);
      *(float4*)(wLDS + c * 128 + col4 * 4) = v;
    }
    __syncthreads();
#pragma unroll 4
    for (int c = 0; c < 32; ++c) {
      float a[8];
#pragma unroll
      for (int r = 0; r < 8; ++r) a[r] = fLDS[(ty * 8 + r) * 65 + kk + c];
      float4 b0 = *(const float4*)(wLDS + c * 128 + tx * 8);
      float4 b1 = *(const float4*)(wLDS + c * 128 + tx * 8 + 4);
      float b[8] = {b0.x, b0.y, b0.z, b0.w, b1.x, b1.y, b1.z, b1.w};
#pragma unroll
      for (int r = 0; r < 8; ++r)
#pragma unroll
        for (int j = 0; j < 8; ++j) acc[r][j] += a[r] * b[j];
    }
  }
#pragma unroll
  for (int r = 0; r < 8; ++r) {
    int p = p0 + ty * 8 + r;
    if (p < pm) {
      uint4 pk;
      pk.x = f2bf_pack(acc[r][0], acc[r][1]);
      pk.y = f2bf_pack(acc[r][2], acc[r][3]);
      pk.z = f2bf_pack(acc[r][4], acc[r][5]);
      pk.w = f2bf_pack(acc[r][6], acc[r][7]);
      *(uint4*)(msgbuf + ((size_t)i * pm + p) * 128 + tx * 8) = pk;
    }
  }
}

__global__ __launch_bounds__(256) void msg_gemm(
    const float* __restrict__ f1, const float* __restrict__ f2,
    const float* __restrict__ W27, const int* __restrict__ G,
    const int* __restrict__ S, float* __restrict__ out,
    int N, int N1, int pm) {
  const int i = blockIdx.y;
  const int ktap = i + (i >= 13 ? 1 : 0);
  const float* W = W27 + (size_t)ktap * 64 * 128;
  const int* Gi = G + (size_t)i * pm;
  const int* Si = S + (size_t)i * pm;
  const int p0 = blockIdx.x * 128;
  if (Si[p0] >= N) return;
  __shared__ float fLDS[128 * 65];
  __shared__ float wLDS[32 * 128];
  const int tid = threadIdx.x;
  const int tx = tid & 15, ty = tid >> 4;
  for (int k = 0; k < 8; ++k) {
    int flat4 = tid + k * 256;
    int row = flat4 >> 4, c4 = flat4 & 15;
    int p = p0 + row;
    float4 v = make_float4(0.f, 0.f, 0.f, 0.f);
    if (p < pm) {
      int g = Gi[p];
      if (g < N) {
        const float* src = (g < N1) ? (f1 + (size_t)g * 64)
                                    : (f2 + (size_t)(g - N1) * 64);
        v = *(const float4*)(src + c4 * 4);
      }
    }
    int l = row * 65 + c4 * 4;
    fLDS[l + 0] = v.x; fLDS[l + 1] = v.y; fLDS[l + 2] = v.z; fLDS[l + 3] = v.w;
  }
  float acc[8][8];
#pragma unroll
  for (int r = 0; r < 8; ++r)
#pragma unroll
    for (int j = 0; j < 8; ++j) acc[r][j] = 0.f;
  for (int kk = 0; kk < 64; kk += 32) {
    __syncthreads();
    for (int k = 0; k < 4; ++k) {
      int flat4 = tid + k * 256;
      int c = flat4 >> 5, col4 = flat4 & 31;
      float4 v = *(const float4*)(W + (size_t)(kk + c) * 128 + col4 * 4);
      *(float4*)(wLDS + c * 128 + col4 * 4) = v;
    }
    __syncthreads();
#pragma unroll 4
    for (int c = 0; c < 32; ++c) {
      float a[8];
#pragma unroll
      for (int r = 0; r < 8; ++r) a[r] = fLDS[(ty * 8 + r) * 65 + kk + c];
      float4 b0 = *(const float4*)(wLDS + c * 128 + tx * 8);
      float4 b1 = *(const float4*)(wLDS + c * 128 + tx * 8 + 4);
      float b[8] = {b0.x, b0.y, b0.z, b0.w, b1.x, b1.y, b1.z, b1.w};
#pragma unroll
      for (int r = 0; r < 8; ++r)
#pragma unroll
        for (int j = 0; j < 8; ++j) acc[r][j] += a[r] * b[j];
    }
  }
#pragma unroll
  for (int r = 0; r < 8; ++r) {
    int p = p0 + ty * 8 + r;
    if (p < pm) {
      int s = Si[p];
      if (s < N) {
        float* dst = out + (size_t)s * 128 + tx * 8;
#pragma unroll
        for (int j = 0; j < 8; ++j) unsafeAtomicAdd(dst + j, acc[r][j]);
      }
    }
  }
}

__global__ __launch_bounds__(256) void combine_stats(
    float* __restrict__ out, const int* __restrict__ R,
    const unsigned short* __restrict__ msgbuf, float* __restrict__ ws,
    int N) {
  const int tid = threadIdx.x;
  const int grp = tid >> 5, l = tid & 31;
  const int base = tid & 32;
  float4 s = make_float4(0.f, 0.f, 0.f, 0.f);
  float4 q = make_float4(0.f, 0.f, 0.f, 0.f);
  for (int j = blockIdx.x * 8 + grp; j < N; j += gridDim.x * 8) {
    float4 v = ((const float4*)(out + (size_t)j * 128))[l];
    int r = (l < 26) ? R[(size_t)j * 26 + l] : -1;
    unsigned long long bal = __ballot(r >= 0);
    unsigned mym = (unsigned)((bal >> base) & 0x3FFFFFFull);
    const bool any = (mym != 0);
    while (mym) {
      int b = __builtin_ctz(mym);
      mym &= mym - 1;
      int ptr = __shfl(r, base + b, 64);
      uint2 mv = ((const uint2*)(msgbuf + (size_t)ptr * 128))[l];
      v.x += bf2f(mv.x & 0xffffu);
      v.y += bf2f(mv.x >> 16);
      v.z += bf2f(mv.y & 0xffffu);
      v.w += bf2f(mv.y >> 16);
    }
    if (any) ((float4*)(out + (size_t)j * 128))[l] = v;
    s.x += v.x; s.y += v.y; s.z += v.z; s.w += v.w;
    q.x += v.x * v.x; q.y += v.y * v.y; q.z += v.z * v.z; q.w += v.w * v.w;
  }
  __shared__ float red[8 * 32 * 8];
  float* my = red + (grp * 32 + l) * 8;
  my[0] = s.x; my[1] = s.y; my[2] = s.z; my[3] = s.w;
  my[4] = q.x; my[5] = q.y; my[6] = q.z; my[7] = q.w;
  __syncthreads();
  {
    int c4 = tid & 31, j = tid >> 5;
    float v = 0.f;
#pragma unroll
    for (int g = 0; g < 8; ++g) v += red[(g * 32 + c4) * 8 + j];
    int col = c4 * 4 + (j & 3);
    unsafeAtomicAdd(&ws[col + (j >> 2) * 128], v);
  }
}

__global__ __launch_bounds__(256) void stats_kernel(
    const float* __restrict__ out, float* __restrict__ ws, int total4) {
  const int tid = threadIdx.x;
  float4 s = make_float4(0.f, 0.f, 0.f, 0.f);
  float4 q = make_float4(0.f, 0.f, 0.f, 0.f);
  const float4* o4 = (const float4*)out;
  for (int idx = blockIdx.x * 256 + tid; idx < total4; idx += gridDim.x * 256) {
    float4 v = o4[idx];
    s.x += v.x; s.y += v.y; s.z += v.z; s.w += v.w;
    q.x += v.x * v.x; q.y += v.y * v.y; q.z += v.z * v.z; q.w += v.w * v.w;
  }
  __shared__ float red[8 * 32 * 8];
  const int col4 = tid & 31, grpq = tid >> 5;
  float* my = red + (grpq * 32 + col4) * 8;
  my[0] = s.x; my[1] = s.y; my[2] = s.z; my[3] = s.w;
  my[4] = q.x; my[5] = q.y; my[6] = q.z; my[7] = q.w;
  __syncthreads();
  {
    int c4 = tid & 31, j = tid >> 5;
    float v = 0.f;
#pragma unroll
    for (int g = 0; g < 8; ++g) v += red[(g * 32 + c4) * 8 + j];
    int col = c4 * 4 + (j & 3);
    unsafeAtomicAdd(&ws[col + (j >> 2) * 128], v);
  }
}

__global__ __launch_bounds__(256) void norm_kernel(
    float* __restrict__ out, const float* __restrict__ ws,
    const float* __restrict__ gamma, const float* __restrict__ beta,
    int total4, float invN) {
  const int tid = threadIdx.x;
  const int c4 = tid & 31;
  float4 s = ((const float4*)ws)[c4];
  float4 q = ((const float4*)ws)[32 + c4];
  float4 g = ((const float4*)gamma)[c4];
  float4 b = ((const float4*)beta)[c4];
  float m0 = s.x * invN, m1 = s.y * invN, m2 = s.z * invN, m3 = s.w * invN;
  float sc0 = g.x * rsqrtf(q.x * invN - m0 * m0 + EPS);
  float sc1 = g.y * rsqrtf(q.y * invN - m1 * m1 + EPS);
  float sc2 = g.z * rsqrtf(q.z * invN - m2 * m2 + EPS);
  float sc3 = g.w * rsqrtf(q.w * invN - m3 * m3 + EPS);
  float sh0 = b.x - m0 * sc0, sh1 = b.y - m1 * sc1;
  float sh2 = b.z - m2 * sc2, sh3 = b.w - m3 * sc3;
  float4* o4 = (float4*)out;
  for (int idx = blockIdx.x * 256 + tid; idx < total4; idx += gridDim.x * 256) {
    float4 v = o4[idx];
    v.x = fmaxf(v.x * sc0 + sh0, 0.f);
    v.y = fmaxf(v.y * sc1 + sh1, 0.f);
    v.z = fmaxf(v.z * sc2 + sh2, 0.f);
    v.w = fmaxf(v.w * sc3 + sh3, 0.f);
    o4[idx] = v;
  }
}

// ===========================================================================
extern "C" void kernel_launch(void* const* d_in, const int* in_sizes, int n_in,
                              void* d_out, int out_size, void* d_ws, size_t ws_size,
                              hipStream_t stream) {
  const float* f1 = (const float*)d_in[0];
  const float* f2 = (const float*)d_in[1];
  const float* W = (const float*)d_in[2];
  const float* bias = (const float*)d_in[3];
  const float* gamma = (const float*)d_in[4];
  const float* beta = (const float*)d_in[5];
  const int* G = (const int*)d_in[6];
  const int* S = (const int*)d_in[7];
  const int N1 = in_sizes[0] / 64;
  const int N2 = in_sizes[1] / 64;
  const int N = N1 + N2;
  const int pm = in_sizes[6] / 26;
  float* out = (float*)d_out;
  float* ws = (float*)d_ws;

  const size_t AL = 255;
  // full path layout (padded stats + gtot in first 32 KB; cnt right after
  // so one memset covers both)
  const size_t offC = 32768;                       // cnt: N ints
  const size_t Cb = (size_t)N * 4;
  const size_t offBC = (offC + Cb + AL) & ~AL;     // BC: N int2
  const size_t BCb = (size_t)N * 8;
  const size_t offSL = (offBC + BCb + AL) & ~AL;   // SL: 26*pm bytes
  const size_t SLb = (size_t)26 * pm;
  const size_t offF = (offSL + SLb + AL) & ~AL;    // fbuf: (N+1) x 64 bf16
  const size_t Fb = (size_t)(N + 1) * 64 * 2;
  const size_t offW = (offF + Fb + AL) & ~AL;
  const size_t Wbyt = (size_t)27 * 128 * 64 * 2;
  const size_t offM = (offW + Wbyt + AL) & ~AL;
  const size_t Mb = (size_t)26 * pm * 128 * 2;     // compact (messages only)
  const size_t offO = (offM + Mb + AL) & ~AL;
  const size_t Ob = (size_t)N * 128 * 2;
  const bool full = ws_size >= offO + Ob;

  // fp32 fallback layout (unpadded stats: 1 KB)
  const size_t Rb = (size_t)N * 26 * 4;
  const size_t offR2 = 1024;
  const size_t offM2 = (offR2 + Rb + AL) & ~AL;
  const bool fast2 = ws_size >= offM2 + Mb;

  if (full) {
    int* cnt = (int*)((char*)d_ws + offC);
    int2* BC = (int2*)((char*)d_ws + offBC);
    unsigned char* SLp = (unsigned char*)((char*)d_ws + offSL);
    unsigned short* fbuf = (unsigned short*)((char*)d_ws + offF);
    unsigned short* Wb = (unsigned short*)((char*)d_ws + offW);
    unsigned short* compact = (unsigned short*)((char*)d_ws + offM);
    unsigned short* outb = (unsigned short*)((char*)d_ws + offO);
    int* gtot = (int*)((char*)d_ws + 28672);  // inside zeroed stats block

    const int wblocks = (27 * 128 * 64) / 256;     // 864
    const int fblocks = ((N + 1) * 8 + 255) / 256;
    const int cpb256 = (pm + 255) / 256;
    const int cpb128 = (pm + 127) / 128;
    const int cblocks = (N + 127) / 128;

    (void)hipMemsetAsync(ws, 0, offC + Cb, stream);  // stats + gtot + cnt
    prep<<<wblocks + fblocks + 26 * cpb256, 256, 0, stream>>>(
        W, Wb, f1, f2, fbuf, S, SLp, cnt, N, N1, pm, wblocks, fblocks,
        cpb256);
    prefix_base<<<(N + 1023) / 1024, 256, 0, stream>>>(cnt, BC, gtot, N);
    msg_mfma_c<<<dim3(cpb128, 26), 256, 0, stream>>>(
        fbuf, Wb, G, S, BC, SLp, compact, N, pm);
    center_combine<<<cblocks, 256, 0, stream>>>(
        fbuf, Wb + (size_t)13 * 128 * 64, bias, BC, compact, outb, ws, N);
    norm_b<<<2048, 256, 0, stream>>>(outb, out, ws, gamma, beta, N * 16,
                                     1.0f / N);
  } else if (fast2) {
    int* R = (int*)((char*)d_ws + offR2);
    unsigned short* msgbuf = (unsigned short*)((char*)d_ws + offM2);
    (void)hipMemsetAsync(ws, 0, 256 * sizeof(float), stream);
    (void)hipMemsetAsync(R, 0xFF, Rb, stream);
    center_gemm<<<(N + 127) / 128, 256, 0, stream>>>(
        f1, f2, W + (size_t)13 * 64 * 128, bias, out, N, N1);
    scatter_R<<<dim3((pm + 255) / 256, 26), 256, 0, stream>>>(S, R, N, pm);
    msg_gemm_buf<<<dim3((pm + 127) / 128, 26), 256, 0, stream>>>(
        f1, f2, W, G, S, msgbuf, N, N1, pm);
    combine_stats<<<1024, 256, 0, stream>>>(out, R, msgbuf, ws, N);
    norm_kernel<<<2048, 256, 0, stream>>>(out, ws, gamma, beta, N * 32,
                                          1.0f / N);
  } else {
    (void)hipMemsetAsync(ws, 0, 256 * sizeof(float), stream);
    center_gemm<<<(N + 127) / 128, 256, 0, stream>>>(
        f1, f2, W + (size_t)13 * 64 * 128, bias, out, N, N1);
    msg_gemm<<<dim3((pm + 127) / 128, 26), 256, 0, stream>>>(
        f1, f2, W, G, S, out, N, N1, pm);
    stats_kernel<<<1024, 256, 0, stream>>>(out, ws, N * 32);
    norm_kernel<<<2048, 256, 0, stream>>>(out, ws, gamma, beta, N * 32,
                                          1.0f / N);
  }
}